// Round 1
// baseline (1428.039 us; speedup 1.0000x reference)
//
#include <hip/hip_runtime.h>

// MOGCN on MI355X. Pipeline:
//  k_build_wb : W[3,3,512,256] (+ W@a1, W@a2 cols) -> bf16, k-swizzled [64][2432][8]
//  k_xconv    : X fp32 -> bf16, k-swizzled [64][16384][8]
//  k_bitpack  : adj>0 -> bitset masks (level0), two layouts
//  k_boolmm   : boolean matrix power masks (adj^2>0, adj^3>0) via u64 OR-gather
//  k_gemm_h   : [16384,512]@[512,2432] bf16 MFMA -> h (swizzled) + f1/f2 (fp32)
//  k_rowstats : per-row softmax stats -> C=-m*log2e-log2(l), Z (empty-row handling)
//  k_attgemm  : fused masked-softmax @ h : P generated in registers -> MFMA, atomic H
//  k_score    : s = tanh(H@Ww+bw)@Wc
//  k_combine  : softmax over layers, weighted sum -> out
//
// Workspace map (bytes), total 159,842,304 (~152.4 MiB):
//  [0)            Xs bf16 16,777,216 | Wb bf16 @16,777,216 (2,490,368)  -- dead after k_gemm_h
//  [0)            H32 fp32 50,331,648 (reuses region above; memset after k_gemm_h)
//  [50,331,648)   hsw bf16 75,497,472   [9][16][128][256][8]
//  [125,829,120)  mbA u64 12,582,912    [2 lvl][48][1024][16]
//  [138,412,032)  mbT u64 18,874,368    [9][16][16w][1024i]
//  [157,286,400)  fbuf fp32 1,179,648   [2][9][16384]
//  [158,466,048)  rowC 589,824 | [159,055,872) rowZ 589,824 | [159,645,696) svals 196,608

typedef unsigned long long u64;
typedef __attribute__((ext_vector_type(4))) float f32x4;
typedef __attribute__((ext_vector_type(8))) short bf16x8;

#define NEGF (-9.0e15f)
#define L2E 1.44269504f

__device__ __forceinline__ float fexp2(float x){
#if __has_builtin(__builtin_amdgcn_exp2f)
  return __builtin_amdgcn_exp2f(x);
#else
  return exp2f(x);
#endif
}
__device__ __forceinline__ float flog2(float x){
#if __has_builtin(__builtin_amdgcn_logf)
  return __builtin_amdgcn_logf(x);
#else
  return log2f(x);
#endif
}
__device__ __forceinline__ float frcp(float x){
#if __has_builtin(__builtin_amdgcn_rcpf)
  return __builtin_amdgcn_rcpf(x);
#else
  return 1.0f/x;
#endif
}
__device__ __forceinline__ unsigned short f2bf(float x){   // RNE
  union { float f; unsigned u; } a; a.f = x;
  unsigned r = a.u + 0x7FFFu + ((a.u >> 16) & 1u);
  return (unsigned short)(r >> 16);
}
__device__ __forceinline__ float bf2f(unsigned short h){
  union { unsigned u; float f; } a; a.u = ((unsigned)h) << 16; return a.f;
}
__device__ __forceinline__ unsigned pack_bf16x2(float lo, float hi){ // fast round
  union { float f; unsigned u; } a, b; a.f = lo; b.f = hi;
  unsigned ul = a.u + 0x8000u, uh = b.u + 0x8000u;
#if __has_builtin(__builtin_amdgcn_perm)
  return __builtin_amdgcn_perm(uh, ul, 0x07060302u);
#else
  return (ul >> 16) | (uh & 0xFFFF0000u);
#endif
}
__device__ __forceinline__ float tanh_fast(float x){
  float e = fexp2(x * 2.885390082f);  // exp(2x)
  return 1.0f - 2.0f*frcp(e + 1.0f);
}
__device__ __forceinline__ void async_cp16(void* lds, const void* g){
  __builtin_amdgcn_global_load_lds(
      (const __attribute__((address_space(1))) unsigned int*)g,
      (__attribute__((address_space(3))) unsigned int*)lds, 16, 0, 0);
}

// ---------------- prep kernels ----------------

__global__ void k_build_wb(const float* __restrict__ W, const float* __restrict__ a1,
                           const float* __restrict__ a2, unsigned short* __restrict__ Wb)
{
  int idx = blockIdx.x*256 + threadIdx.x;           // g*2432 + c
  if (idx >= 64*2432) return;
  int c = idx % 2432, g = idx / 2432;
  unsigned short o[8];
  if (c < 2304) {
    int s = c >> 8, f = c & 255, t = s % 3, klq = s / 3;   // s = kl*3 + t
    const float* wp = W + ((size_t)(t*3 + klq)*512)*256 + f;
#pragma unroll
    for (int e = 0; e < 8; ++e) o[e] = f2bf(wp[(size_t)(g*8 + e)*256]);
  } else if (c < 2322) {
    int c2 = c - 2304, s = c2 >> 1, t = s % 3, klq = s / 3;
    const float* av = ((c2 & 1) ? a2 : a1) + (t*3 + klq)*256;
    const float* wp = W + ((size_t)(t*3 + klq)*512)*256;
#pragma unroll
    for (int e = 0; e < 8; ++e) {
      float acc = 0.0f;
      const float* wr = wp + (size_t)(g*8 + e)*256;
      for (int f = 0; f < 256; ++f) acc += wr[f]*av[f];
      o[e] = f2bf(acc);
    }
  } else {
#pragma unroll
    for (int e = 0; e < 8; ++e) o[e] = 0;
  }
  ushort4 lo, hi;
  lo.x=o[0]; lo.y=o[1]; lo.z=o[2]; lo.w=o[3];
  hi.x=o[4]; hi.y=o[5]; hi.z=o[6]; hi.w=o[7];
  ushort4* dst = (ushort4*)(Wb + (size_t)idx*8);
  dst[0] = lo; dst[1] = hi;
}

__global__ void k_xconv(const float* __restrict__ X, unsigned short* __restrict__ Xs)
{
  int idx = blockIdx.x*256 + threadIdx.x;           // g*16384 + bn
  int bn = idx & 16383, g = idx >> 14;
  const float* xp = X + (size_t)bn*512 + g*8;
  ushort4 lo, hi;
  lo.x=f2bf(xp[0]); lo.y=f2bf(xp[1]); lo.z=f2bf(xp[2]); lo.w=f2bf(xp[3]);
  hi.x=f2bf(xp[4]); hi.y=f2bf(xp[5]); hi.z=f2bf(xp[6]); hi.w=f2bf(xp[7]);
  ushort4* dst = (ushort4*)(Xs + (size_t)idx*8);
  dst[0] = lo; dst[1] = hi;
}

__global__ void k_bitpack(const float* __restrict__ adj, u64* __restrict__ mbA0,
                          u64* __restrict__ mbT)
{
  size_t tid = (size_t)blockIdx.x*256 + threadIdx.x;  // adj[b][t][i][j]
  float v = adj[tid];
  u64 msk = __ballot(v > 0.0f);
  if ((threadIdx.x & 63) == 0) {
    size_t word = tid >> 6;
    int w = (int)(word & 15), i = (int)((word >> 4) & 1023);
    int bt = (int)(word >> 14);     // b*3 + t
    int t = bt % 3, b = bt / 3;
    mbA0[((size_t)(t*16 + b)*1024 + i)*16 + w] = msk;
    mbT[(((size_t)t*16 + b)*16 + w)*1024 + i] = msk;   // s = t for level 0
  }
}

__global__ void k_boolmm(const u64* __restrict__ A, const u64* __restrict__ Bm,
                         u64* __restrict__ outA, u64* __restrict__ outT, int sbase)
{
  int tid = blockIdx.x*256 + threadIdx.x;   // 48*1024*16
  int w = tid & 15, i = (tid >> 4) & 1023, tb = tid >> 14;
  const u64* Ar = A + ((size_t)tb*1024 + i)*16;
  const u64* Bb = Bm + (size_t)tb*16384;
  u64 acc = 0;
  for (int ww = 0; ww < 16; ++ww) {
    u64 aw = Ar[ww];
    while (aw) {
      int kk = __builtin_ctzll(aw);
      aw &= aw - 1;
      acc |= Bb[((size_t)(ww*64 + kk))*16 + w];
    }
  }
  if (outA) outA[((size_t)tb*1024 + i)*16 + w] = acc;
  int t = tb >> 4, bq = tb & 15;
  outT[(((size_t)(sbase + t)*16 + bq)*16 + w)*1024 + i] = acc;
}

// ---------------- h = X@W GEMM (bf16 MFMA), fused f1/f2 ----------------

__global__ __launch_bounds__(256) void k_gemm_h(
    const unsigned short* __restrict__ Xs, const unsigned short* __restrict__ Wb,
    unsigned short* __restrict__ hsw, float* __restrict__ fbuf)
{
  __shared__ unsigned short Asl[8*132*8 + 8];
  __shared__ unsigned short Bsl[8*132*8 + 8];
  const int tid = threadIdx.x, lane = tid & 63, wid = tid >> 6;
  int vb = blockIdx.x;                       // XCD swizzle: same mt -> same XCD
  int xc = vb & 7, mrest = vb >> 3;
  int mt = xc + 8*(mrest/19), nt = mrest % 19;
  const int M0 = mt << 7, N0 = nt << 7;
  const int wr = (wid >> 1) << 6, wc = (wid & 1) << 6;
  const int me = lane & 15;
  f32x4 acc[4][4] = {};
  for (int ks64 = 0; ks64 < 8; ++ks64) {
    __syncthreads();
#pragma unroll
    for (int c = 0; c < 4; ++c) {
      int chunk = wid*4 + c, g = chunk >> 1, hh = chunk & 1;
      int ldsoff = (g*132 + hh*64)*8;
      const unsigned short* gpA = Xs + ((size_t)(ks64*8 + g)*16384 + (M0 + hh*64 + lane))*8;
      async_cp16(Asl + ldsoff, gpA);
      const unsigned short* gpB = Wb + ((size_t)(ks64*8 + g)*2432 + (N0 + hh*64 + lane))*8;
      async_cp16(Bsl + ldsoff, gpB);
    }
    __syncthreads();
#pragma unroll
    for (int ks32 = 0; ks32 < 2; ++ks32) {
      const int kg = ks32*4 + (lane >> 4);
      bf16x8 afr[4], bfr[4];
#pragma unroll
      for (int rb = 0; rb < 4; ++rb)
        afr[rb] = *(const bf16x8*)(Asl + (kg*132 + wr + rb*16 + me)*8);
#pragma unroll
      for (int cb = 0; cb < 4; ++cb)
        bfr[cb] = *(const bf16x8*)(Bsl + (kg*132 + wc + cb*16 + me)*8);
#pragma unroll
      for (int rb = 0; rb < 4; ++rb)
#pragma unroll
        for (int cb = 0; cb < 4; ++cb)
          acc[rb][cb] = __builtin_amdgcn_mfma_f32_16x16x32_bf16(afr[rb], bfr[cb], acc[rb][cb], 0, 0, 0);
    }
  }
  const int quad = lane >> 4;
#pragma unroll
  for (int rb = 0; rb < 4; ++rb) {
    int jbase = M0 + wr + rb*16 + quad*4;
    int bidx = jbase >> 10, jn = jbase & 1023;
#pragma unroll
    for (int cb = 0; cb < 4; ++cb) {
      int c = N0 + wc + cb*16 + me;
      f32x4 v = acc[rb][cb];
      if (c < 2304) {
        int s = c >> 8, f = c & 255;
        ushort4 pk;
        pk.x = f2bf(v[0]); pk.y = f2bf(v[1]); pk.z = f2bf(v[2]); pk.w = f2bf(v[3]);
        *(ushort4*)(hsw + (size_t)s*4194304 + (size_t)bidx*262144 + ((jn>>3)*256 + f)*8 + (jn&7)) = pk;
      } else if (c < 2322) {
        int c2 = c - 2304, s = c2 >> 1, wh = c2 & 1;
        *(f32x4*)(fbuf + (size_t)wh*147456 + s*16384 + jbase) = v;
      }
    }
  }
}

// ---------------- per-row softmax stats ----------------

__global__ __launch_bounds__(256) void k_rowstats(
    const u64* __restrict__ mbT, const float* __restrict__ fbuf,
    float* __restrict__ rowC, float* __restrict__ rowZ)
{
  int gw = blockIdx.x*4 + (threadIdx.x >> 6);   // row id: (s*16+b)*1024 + i
  int lane = threadIdx.x & 63;
  int i = gw & 1023, sb = gw >> 10;
  int b = sb & 15, s = sb >> 4;
  const u64* mrow = mbT + (size_t)sb*16384 + i;
  const float* f1g = fbuf + s*16384 + b*1024;
  const float* f2g = fbuf + 147456 + s*16384 + b*1024;
  float f1i = f1g[i];
  float vals[16];
  float mmax = NEGF;
#pragma unroll
  for (int w = 0; w < 16; ++w) {
    u64 word = mrow[(size_t)w*1024];
    float f2v = f2g[w*64 + lane];
    float sv = f1i + f2v;
    float lk = fmaxf(sv, 0.2f*sv);
    float val = ((word >> lane) & 1ull) ? lk : NEGF;
    vals[w] = val;
    mmax = fmaxf(mmax, val);
  }
#pragma unroll
  for (int off = 32; off; off >>= 1) mmax = fmaxf(mmax, __shfl_xor(mmax, off));
  float l = 0.0f;
#pragma unroll
  for (int w = 0; w < 16; ++w) l += fexp2((vals[w] - mmax)*L2E);
#pragma unroll
  for (int off = 32; off; off >>= 1) l += __shfl_xor(l, off);
  if (lane == 0) {
    bool empty = (mmax < -8.0e15f);
    rowC[gw] = (empty ? 0.0f : -mmax*L2E) - flog2(l);
    rowZ[gw] = empty ? 0.0f : NEGF;
  }
}

// ---------------- fused attention GEMM: H += softmax(mask(e)) @ h ----------------

__global__ __launch_bounds__(128, 2) void k_attgemm(
    const unsigned short* __restrict__ hsw, const float* __restrict__ fbuf,
    const float* __restrict__ rowC, const float* __restrict__ rowZ,
    const u64* __restrict__ mbT, float* __restrict__ H32)
{
  __shared__ unsigned short Bt[8*260*8];   // h tile [8 kgrp][260 f pad][8]
  __shared__ float f2s[64];
  const int tid = threadIdx.x, lane = tid & 63, wid = tid >> 6;
  int vb = blockIdx.x;                      // swizzle: same (s,b) group -> same XCD
  int xc = vb & 7, m = vb >> 3;
  int g = xc + 8*(m >> 4), mt = m & 15;
  int s = g >> 4, b = g & 15;
  int kl = s / 3;
  const int i0w = mt*64 + wid*32;
  const int me = lane & 15, quad = lane >> 4;
  const float* f1g = fbuf + s*16384 + b*1024;
  const float* f2g = fbuf + 147456 + s*16384 + b*1024;
  const float* Cg = rowC + (s*16 + b)*1024;
  const float* Zg = rowZ + (s*16 + b)*1024;
  const u64* mrow = mbT + (size_t)(s*16 + b)*16384;
  const unsigned short* hb = hsw + (size_t)s*4194304 + (size_t)b*262144;
  const int ir0 = i0w + me, ir1 = i0w + 16 + me;
  float f1v[2] = { f1g[ir0], f1g[ir1] };
  float Cv[2]  = { Cg[ir0],  Cg[ir1]  };
  float Zv[2]  = { Zg[ir0],  Zg[ir1]  };
  f32x4 acc[2][16] = {};
  for (int st = 0; st < 16; ++st) {
    u64 mw0 = mrow[st*1024 + ir0];
    u64 mw1 = mrow[st*1024 + ir1];
    __syncthreads();
    if (tid < 64) f2s[tid] = f2g[st*64 + tid];
    const unsigned short* hstage = hb + st*16384;
#pragma unroll
    for (int cc = 0; cc < 16; ++cc) {
      int gq = cc*2 + wid, gg = gq >> 2, q = gq & 3;
      async_cp16((void*)(Bt + gg*2080 + q*512), hstage + gg*2048 + q*512 + lane*8);
    }
    __syncthreads();
#pragma unroll
    for (int ks = 0; ks < 2; ++ks) {
      int kloc = ks*32 + quad*8;
      float4 fa = *(const float4*)(f2s + kloc);
      float4 fb4 = *(const float4*)(f2s + kloc + 4);
      float f2e[8] = {fa.x, fa.y, fa.z, fa.w, fb4.x, fb4.y, fb4.z, fb4.w};
      bf16x8 af[2];
#pragma unroll
      for (int rb = 0; rb < 2; ++rb) {
        unsigned mby = (unsigned)(((rb ? mw1 : mw0) >> kloc) & 0xFFull);
        union { bf16x8 v; unsigned u[4]; } ua;
#pragma unroll
        for (int p = 0; p < 4; ++p) {
          float s0 = f1v[rb] + f2e[2*p];
          float l0 = fmaxf(s0, 0.2f*s0);
          float v0 = (mby & (1u << (2*p))) ? l0 : Zv[rb];
          float p0 = fexp2(__builtin_fmaf(v0, L2E, Cv[rb]));
          float s1 = f1v[rb] + f2e[2*p+1];
          float l1 = fmaxf(s1, 0.2f*s1);
          float v1 = (mby & (2u << (2*p))) ? l1 : Zv[rb];
          float p1 = fexp2(__builtin_fmaf(v1, L2E, Cv[rb]));
          ua.u[p] = pack_bf16x2(p0, p1);
        }
        af[rb] = ua.v;
      }
      int gg = ks*4 + quad;
#pragma unroll
      for (int cb = 0; cb < 16; ++cb) {
        bf16x8 bf = *(const bf16x8*)(Bt + (gg*260 + cb*16 + me)*8);
        acc[0][cb] = __builtin_amdgcn_mfma_f32_16x16x32_bf16(af[0], bf, acc[0][cb], 0, 0, 0);
        acc[1][cb] = __builtin_amdgcn_mfma_f32_16x16x32_bf16(af[1], bf, acc[1][cb], 0, 0, 0);
      }
    }
  }
#pragma unroll
  for (int rb = 0; rb < 2; ++rb) {
    int io = i0w + rb*16 + quad*4;
#pragma unroll
    for (int cb = 0; cb < 16; ++cb) {
      int f = cb*16 + me;
      float* hp = H32 + (((size_t)b*1024 + io)*3 + kl)*256 + f;
#pragma unroll
      for (int r = 0; r < 4; ++r)
        atomicAdd(hp + (size_t)r*768, acc[rb][cb][r]);
    }
  }
}

// ---------------- layer attention: s = tanh(H@Ww+bw)@Wc ----------------

__global__ __launch_bounds__(256) void k_score(
    const float* __restrict__ H32, const float* __restrict__ Ww,
    const float* __restrict__ bwv, const float* __restrict__ Wcv, float* __restrict__ svals)
{
  __shared__ unsigned short WwL[25664];
  __shared__ float bwL[128], WcL[128];
  int tid = threadIdx.x;
  for (int ix = tid; ix < 25600; ix += 256) WwL[ix] = f2bf(Ww[ix]);
  for (int ix = 25600 + tid; ix < 25664; ix += 256) WwL[ix] = 0;
  if (tid < 100) { bwL[tid] = bwv[tid]; WcL[tid] = Wcv[tid]; }
  if (tid >= 100 && tid < 128) { bwL[tid] = 0.0f; WcL[tid] = 0.0f; }
  __syncthreads();
  int lane = tid & 63, wid = tid >> 6;
  int c0 = lane, c1 = lane + 64;
  for (int rr = 0; rr < 64; ++rr) {
    int row = blockIdx.x*256 + wid*64 + rr;
    int rowu = __builtin_amdgcn_readfirstlane(row);
    const float* Hrow = H32 + (size_t)rowu*256;
    float a0 = 0.f, a1v = 0.f;
    for (int ff = 0; ff < 256; ++ff) {
      float hv = Hrow[ff];
      a0  = __builtin_fmaf(hv, bf2f(WwL[ff*100 + c0]), a0);
      a1v = __builtin_fmaf(hv, bf2f(WwL[ff*100 + c1]), a1v);
    }
    float contrib = tanh_fast(a0 + bwL[c0]) * WcL[c0];
    if (c1 < 100) contrib += tanh_fast(a1v + bwL[c1]) * WcL[c1];
#pragma unroll
    for (int off = 32; off; off >>= 1) contrib += __shfl_xor(contrib, off);
    if (lane == 0) svals[rowu] = contrib;
  }
}

__global__ void k_combine(const float* __restrict__ svals, const float* __restrict__ H32,
                          float* __restrict__ out)
{
  int tid = blockIdx.x*256 + threadIdx.x;
  int fq = tid & 63, bn = tid >> 6;
  float s0 = svals[bn*3], s1 = svals[bn*3+1], s2 = svals[bn*3+2];
  float mm = fmaxf(s0, fmaxf(s1, s2));
  float e0 = fexp2((s0-mm)*L2E), e1 = fexp2((s1-mm)*L2E), e2 = fexp2((s2-mm)*L2E);
  float inv = frcp(e0 + e1 + e2);
  const f32x4* h0 = (const f32x4*)(H32 + (size_t)bn*768) + fq;
  const f32x4* h1 = (const f32x4*)(H32 + (size_t)bn*768 + 256) + fq;
  const f32x4* h2 = (const f32x4*)(H32 + (size_t)bn*768 + 512) + fq;
  f32x4 r = (e0*(*h0) + e1*(*h1) + e2*(*h2))*inv;
  *((f32x4*)out + (size_t)bn*64 + fq) = r;
}

// ---------------- launcher ----------------

extern "C" void kernel_launch(void* const* d_in, const int* in_sizes, int n_in,
                              void* d_out, int out_size, void* d_ws, size_t ws_size,
                              hipStream_t stream) {
  const float* adj = (const float*)d_in[0];
  const float* X   = (const float*)d_in[1];
  const float* W   = (const float*)d_in[2];
  const float* a1  = (const float*)d_in[3];
  const float* a2  = (const float*)d_in[4];
  const float* Ww  = (const float*)d_in[5];
  const float* bw  = (const float*)d_in[6];
  const float* Wc  = (const float*)d_in[7];
  float* out = (float*)d_out;
  char* ws = (char*)d_ws;

  unsigned short* Xs  = (unsigned short*)(ws + 0);
  unsigned short* Wb  = (unsigned short*)(ws + 16777216);
  float* H32          = (float*)(ws + 0);                // reuses Xs/Wb region
  unsigned short* hsw = (unsigned short*)(ws + 50331648);
  u64* mbA            = (u64*)(ws + 125829120);
  u64* mbT            = (u64*)(ws + 138412032);
  float* fbuf         = (float*)(ws + 157286400);
  float* rowC         = (float*)(ws + 158466048);
  float* rowZ         = (float*)(ws + 159055872);
  float* svals        = (float*)(ws + 159645696);

  k_build_wb<<<608, 256, 0, stream>>>(W, a1, a2, Wb);
  k_xconv<<<4096, 256, 0, stream>>>(X, Xs);
  k_bitpack<<<196608, 256, 0, stream>>>(adj, mbA, mbT);
  k_boolmm<<<3072, 256, 0, stream>>>(mbA, mbA, mbA + 786432, mbT, 3);
  k_boolmm<<<3072, 256, 0, stream>>>(mbA + 786432, mbA, (u64*)nullptr, mbT, 6);
  k_gemm_h<<<2432, 256, 0, stream>>>(Xs, Wb, hsw, fbuf);
  hipMemsetAsync(H32, 0, 50331648, stream);
  k_rowstats<<<36864, 256, 0, stream>>>(mbT, fbuf, rowC, rowZ);
  k_attgemm<<<2304, 128, 0, stream>>>(hsw, fbuf, rowC, rowZ, mbT, H32);
  k_score<<<192, 256, 0, stream>>>(H32, Ww, bw, Wc, svals);
  k_combine<<<4096, 256, 0, stream>>>(svals, H32, out);
}

// Round 2
// 960.280 us; speedup vs baseline: 1.4871x; 1.4871x over previous
//
#include <hip/hip_runtime.h>

// MOGCN on MI355X. Pipeline:
//  k_build_wb : W[3,3,512,256] (+ W@a1, W@a2 cols) -> bf16, k-swizzled [64][2432][8]
//  k_xconv    : X fp32 -> bf16, k-swizzled [64][16384][8]
//  k_bitpack  : adj>0 -> bitset masks (level0), two layouts
//  k_boolmm   : boolean matrix power masks (adj^2>0, adj^3>0) via u64 OR-gather
//  k_gemm_h   : [16384,512]@[512,2432] bf16 MFMA -> h (swizzled) + f1/f2 (fp32)
//  k_rowstats : per-row softmax stats -> C=-m*log2e-log2(l), Z (empty-row handling)
//  k_attgemm  : fused masked-softmax @ h : P generated in registers -> MFMA, atomic H
//  k_score    : s = tanh(H@Ww+bw)@Wc  (MFMA GEMM, R1 rewrite)
//  k_combine  : softmax over layers, weighted sum -> out
//
// Workspace map (bytes), total 159,842,304 (~152.4 MiB):
//  [0)            Xs bf16 16,777,216 | Wb bf16 @16,777,216 (2,490,368)  -- dead after k_gemm_h
//  [0)            H32 fp32 50,331,648 (reuses region above; memset after k_gemm_h)
//  [50,331,648)   hsw bf16 75,497,472   [9][16][128][256][8]
//  [125,829,120)  mbA u64 12,582,912    [2 lvl][48][1024][16]
//  [138,412,032)  mbT u64 18,874,368    [9][16][16w][1024i]
//  [157,286,400)  fbuf fp32 1,179,648   [2][9][16384]
//  [158,466,048)  rowC 589,824 | [159,055,872) rowZ 589,824 | [159,645,696) svals 196,608

typedef unsigned long long u64;
typedef __attribute__((ext_vector_type(4))) float f32x4;
typedef __attribute__((ext_vector_type(8))) short bf16x8;

#define NEGF (-9.0e15f)
#define L2E 1.44269504f

__device__ __forceinline__ float fexp2(float x){
#if __has_builtin(__builtin_amdgcn_exp2f)
  return __builtin_amdgcn_exp2f(x);
#else
  return exp2f(x);
#endif
}
__device__ __forceinline__ float flog2(float x){
#if __has_builtin(__builtin_amdgcn_logf)
  return __builtin_amdgcn_logf(x);
#else
  return log2f(x);
#endif
}
__device__ __forceinline__ float frcp(float x){
#if __has_builtin(__builtin_amdgcn_rcpf)
  return __builtin_amdgcn_rcpf(x);
#else
  return 1.0f/x;
#endif
}
__device__ __forceinline__ unsigned short f2bf(float x){   // RNE
  union { float f; unsigned u; } a; a.f = x;
  unsigned r = a.u + 0x7FFFu + ((a.u >> 16) & 1u);
  return (unsigned short)(r >> 16);
}
__device__ __forceinline__ float bf2f(unsigned short h){
  union { unsigned u; float f; } a; a.u = ((unsigned)h) << 16; return a.f;
}
__device__ __forceinline__ unsigned pack_bf16x2(float lo, float hi){ // fast round
  union { float f; unsigned u; } a, b; a.f = lo; b.f = hi;
  unsigned ul = a.u + 0x8000u, uh = b.u + 0x8000u;
#if __has_builtin(__builtin_amdgcn_perm)
  return __builtin_amdgcn_perm(uh, ul, 0x07060302u);
#else
  return (ul >> 16) | (uh & 0xFFFF0000u);
#endif
}
__device__ __forceinline__ float tanh_fast(float x){
  float e = fexp2(x * 2.885390082f);  // exp(2x)
  return 1.0f - 2.0f*frcp(e + 1.0f);
}
__device__ __forceinline__ void async_cp16(void* lds, const void* g){
  __builtin_amdgcn_global_load_lds(
      (const __attribute__((address_space(1))) unsigned int*)g,
      (__attribute__((address_space(3))) unsigned int*)lds, 16, 0, 0);
}

// ---------------- prep kernels ----------------

__global__ void k_build_wb(const float* __restrict__ W, const float* __restrict__ a1,
                           const float* __restrict__ a2, unsigned short* __restrict__ Wb)
{
  int idx = blockIdx.x*256 + threadIdx.x;           // g*2432 + c
  if (idx >= 64*2432) return;
  int c = idx % 2432, g = idx / 2432;
  unsigned short o[8];
  if (c < 2304) {
    int s = c >> 8, f = c & 255, t = s % 3, klq = s / 3;   // s = kl*3 + t
    const float* wp = W + ((size_t)(t*3 + klq)*512)*256 + f;
#pragma unroll
    for (int e = 0; e < 8; ++e) o[e] = f2bf(wp[(size_t)(g*8 + e)*256]);
  } else if (c < 2322) {
    int c2 = c - 2304, s = c2 >> 1, t = s % 3, klq = s / 3;
    const float* av = ((c2 & 1) ? a2 : a1) + (t*3 + klq)*256;
    const float* wp = W + ((size_t)(t*3 + klq)*512)*256;
#pragma unroll
    for (int e = 0; e < 8; ++e) {
      float acc = 0.0f;
      const float* wr = wp + (size_t)(g*8 + e)*256;
      for (int f = 0; f < 256; ++f) acc += wr[f]*av[f];
      o[e] = f2bf(acc);
    }
  } else {
#pragma unroll
    for (int e = 0; e < 8; ++e) o[e] = 0;
  }
  ushort4 lo, hi;
  lo.x=o[0]; lo.y=o[1]; lo.z=o[2]; lo.w=o[3];
  hi.x=o[4]; hi.y=o[5]; hi.z=o[6]; hi.w=o[7];
  ushort4* dst = (ushort4*)(Wb + (size_t)idx*8);
  dst[0] = lo; dst[1] = hi;
}

__global__ void k_xconv(const float* __restrict__ X, unsigned short* __restrict__ Xs)
{
  int idx = blockIdx.x*256 + threadIdx.x;           // g*16384 + bn
  int bn = idx & 16383, g = idx >> 14;
  const float* xp = X + (size_t)bn*512 + g*8;
  ushort4 lo, hi;
  lo.x=f2bf(xp[0]); lo.y=f2bf(xp[1]); lo.z=f2bf(xp[2]); lo.w=f2bf(xp[3]);
  hi.x=f2bf(xp[4]); hi.y=f2bf(xp[5]); hi.z=f2bf(xp[6]); hi.w=f2bf(xp[7]);
  ushort4* dst = (ushort4*)(Xs + (size_t)idx*8);
  dst[0] = lo; dst[1] = hi;
}

__global__ void k_bitpack(const float* __restrict__ adj, u64* __restrict__ mbA0,
                          u64* __restrict__ mbT)
{
  size_t tid = (size_t)blockIdx.x*256 + threadIdx.x;  // adj[b][t][i][j]
  float v = adj[tid];
  u64 msk = __ballot(v > 0.0f);
  if ((threadIdx.x & 63) == 0) {
    size_t word = tid >> 6;
    int w = (int)(word & 15), i = (int)((word >> 4) & 1023);
    int bt = (int)(word >> 14);     // b*3 + t
    int t = bt % 3, b = bt / 3;
    mbA0[((size_t)(t*16 + b)*1024 + i)*16 + w] = msk;
    mbT[(((size_t)t*16 + b)*16 + w)*1024 + i] = msk;   // s = t for level 0
  }
}

__global__ void k_boolmm(const u64* __restrict__ A, const u64* __restrict__ Bm,
                         u64* __restrict__ outA, u64* __restrict__ outT, int sbase)
{
  int tid = blockIdx.x*256 + threadIdx.x;   // 48*1024*16
  int w = tid & 15, i = (tid >> 4) & 1023, tb = tid >> 14;
  const u64* Ar = A + ((size_t)tb*1024 + i)*16;
  const u64* Bb = Bm + (size_t)tb*16384;
  u64 acc = 0;
  for (int ww = 0; ww < 16; ++ww) {
    u64 aw = Ar[ww];
    while (aw) {
      int kk = __builtin_ctzll(aw);
      aw &= aw - 1;
      acc |= Bb[((size_t)(ww*64 + kk))*16 + w];
    }
  }
  if (outA) outA[((size_t)tb*1024 + i)*16 + w] = acc;
  int t = tb >> 4, bq = tb & 15;
  outT[(((size_t)(sbase + t)*16 + bq)*16 + w)*1024 + i] = acc;
}

// ---------------- h = X@W GEMM (bf16 MFMA), fused f1/f2 ----------------

__global__ __launch_bounds__(256) void k_gemm_h(
    const unsigned short* __restrict__ Xs, const unsigned short* __restrict__ Wb,
    unsigned short* __restrict__ hsw, float* __restrict__ fbuf)
{
  __shared__ unsigned short Asl[8*132*8 + 8];
  __shared__ unsigned short Bsl[8*132*8 + 8];
  const int tid = threadIdx.x, lane = tid & 63, wid = tid >> 6;
  int vb = blockIdx.x;                       // XCD swizzle: same mt -> same XCD
  int xc = vb & 7, mrest = vb >> 3;
  int mt = xc + 8*(mrest/19), nt = mrest % 19;
  const int M0 = mt << 7, N0 = nt << 7;
  const int wr = (wid >> 1) << 6, wc = (wid & 1) << 6;
  const int me = lane & 15;
  f32x4 acc[4][4] = {};
  for (int ks64 = 0; ks64 < 8; ++ks64) {
    __syncthreads();
#pragma unroll
    for (int c = 0; c < 4; ++c) {
      int chunk = wid*4 + c, g = chunk >> 1, hh = chunk & 1;
      int ldsoff = (g*132 + hh*64)*8;
      const unsigned short* gpA = Xs + ((size_t)(ks64*8 + g)*16384 + (M0 + hh*64 + lane))*8;
      async_cp16(Asl + ldsoff, gpA);
      const unsigned short* gpB = Wb + ((size_t)(ks64*8 + g)*2432 + (N0 + hh*64 + lane))*8;
      async_cp16(Bsl + ldsoff, gpB);
    }
    __syncthreads();
#pragma unroll
    for (int ks32 = 0; ks32 < 2; ++ks32) {
      const int kg = ks32*4 + (lane >> 4);
      bf16x8 afr[4], bfr[4];
#pragma unroll
      for (int rb = 0; rb < 4; ++rb)
        afr[rb] = *(const bf16x8*)(Asl + (kg*132 + wr + rb*16 + me)*8);
#pragma unroll
      for (int cb = 0; cb < 4; ++cb)
        bfr[cb] = *(const bf16x8*)(Bsl + (kg*132 + wc + cb*16 + me)*8);
#pragma unroll
      for (int rb = 0; rb < 4; ++rb)
#pragma unroll
        for (int cb = 0; cb < 4; ++cb)
          acc[rb][cb] = __builtin_amdgcn_mfma_f32_16x16x32_bf16(afr[rb], bfr[cb], acc[rb][cb], 0, 0, 0);
    }
  }
  const int quad = lane >> 4;
#pragma unroll
  for (int rb = 0; rb < 4; ++rb) {
    int jbase = M0 + wr + rb*16 + quad*4;
    int bidx = jbase >> 10, jn = jbase & 1023;
#pragma unroll
    for (int cb = 0; cb < 4; ++cb) {
      int c = N0 + wc + cb*16 + me;
      f32x4 v = acc[rb][cb];
      if (c < 2304) {
        int s = c >> 8, f = c & 255;
        ushort4 pk;
        pk.x = f2bf(v[0]); pk.y = f2bf(v[1]); pk.z = f2bf(v[2]); pk.w = f2bf(v[3]);
        *(ushort4*)(hsw + (size_t)s*4194304 + (size_t)bidx*262144 + ((jn>>3)*256 + f)*8 + (jn&7)) = pk;
      } else if (c < 2322) {
        int c2 = c - 2304, s = c2 >> 1, wh = c2 & 1;
        *(f32x4*)(fbuf + (size_t)wh*147456 + s*16384 + jbase) = v;
      }
    }
  }
}

// ---------------- per-row softmax stats ----------------

__global__ __launch_bounds__(256) void k_rowstats(
    const u64* __restrict__ mbT, const float* __restrict__ fbuf,
    float* __restrict__ rowC, float* __restrict__ rowZ)
{
  int gw = blockIdx.x*4 + (threadIdx.x >> 6);   // row id: (s*16+b)*1024 + i
  int lane = threadIdx.x & 63;
  int i = gw & 1023, sb = gw >> 10;
  int b = sb & 15, s = sb >> 4;
  const u64* mrow = mbT + (size_t)sb*16384 + i;
  const float* f1g = fbuf + s*16384 + b*1024;
  const float* f2g = fbuf + 147456 + s*16384 + b*1024;
  float f1i = f1g[i];
  float vals[16];
  float mmax = NEGF;
#pragma unroll
  for (int w = 0; w < 16; ++w) {
    u64 word = mrow[(size_t)w*1024];
    float f2v = f2g[w*64 + lane];
    float sv = f1i + f2v;
    float lk = fmaxf(sv, 0.2f*sv);
    float val = ((word >> lane) & 1ull) ? lk : NEGF;
    vals[w] = val;
    mmax = fmaxf(mmax, val);
  }
#pragma unroll
  for (int off = 32; off; off >>= 1) mmax = fmaxf(mmax, __shfl_xor(mmax, off));
  float l = 0.0f;
#pragma unroll
  for (int w = 0; w < 16; ++w) l += fexp2((vals[w] - mmax)*L2E);
#pragma unroll
  for (int off = 32; off; off >>= 1) l += __shfl_xor(l, off);
  if (lane == 0) {
    bool empty = (mmax < -8.0e15f);
    rowC[gw] = (empty ? 0.0f : -mmax*L2E) - flog2(l);
    rowZ[gw] = empty ? 0.0f : NEGF;
  }
}

// ---------------- fused attention GEMM: H += softmax(mask(e)) @ h ----------------

__global__ __launch_bounds__(128, 2) void k_attgemm(
    const unsigned short* __restrict__ hsw, const float* __restrict__ fbuf,
    const float* __restrict__ rowC, const float* __restrict__ rowZ,
    const u64* __restrict__ mbT, float* __restrict__ H32)
{
  __shared__ unsigned short Bt[8*260*8];   // h tile [8 kgrp][260 f pad][8]
  __shared__ float f2s[64];
  const int tid = threadIdx.x, lane = tid & 63, wid = tid >> 6;
  int vb = blockIdx.x;                      // swizzle: same (s,b) group -> same XCD
  int xc = vb & 7, m = vb >> 3;
  int g = xc + 8*(m >> 4), mt = m & 15;
  int s = g >> 4, b = g & 15;
  int kl = s / 3;
  const int i0w = mt*64 + wid*32;
  const int me = lane & 15, quad = lane >> 4;
  const float* f1g = fbuf + s*16384 + b*1024;
  const float* f2g = fbuf + 147456 + s*16384 + b*1024;
  const float* Cg = rowC + (s*16 + b)*1024;
  const float* Zg = rowZ + (s*16 + b)*1024;
  const u64* mrow = mbT + (size_t)(s*16 + b)*16384;
  const unsigned short* hb = hsw + (size_t)s*4194304 + (size_t)b*262144;
  const int ir0 = i0w + me, ir1 = i0w + 16 + me;
  float f1v[2] = { f1g[ir0], f1g[ir1] };
  float Cv[2]  = { Cg[ir0],  Cg[ir1]  };
  float Zv[2]  = { Zg[ir0],  Zg[ir1]  };
  f32x4 acc[2][16] = {};
  for (int st = 0; st < 16; ++st) {
    u64 mw0 = mrow[st*1024 + ir0];
    u64 mw1 = mrow[st*1024 + ir1];
    __syncthreads();
    if (tid < 64) f2s[tid] = f2g[st*64 + tid];
    const unsigned short* hstage = hb + st*16384;
#pragma unroll
    for (int cc = 0; cc < 16; ++cc) {
      int gq = cc*2 + wid, gg = gq >> 2, q = gq & 3;
      async_cp16((void*)(Bt + gg*2080 + q*512), hstage + gg*2048 + q*512 + lane*8);
    }
    __syncthreads();
#pragma unroll
    for (int ks = 0; ks < 2; ++ks) {
      int kloc = ks*32 + quad*8;
      float4 fa = *(const float4*)(f2s + kloc);
      float4 fb4 = *(const float4*)(f2s + kloc + 4);
      float f2e[8] = {fa.x, fa.y, fa.z, fa.w, fb4.x, fb4.y, fb4.z, fb4.w};
      bf16x8 af[2];
#pragma unroll
      for (int rb = 0; rb < 2; ++rb) {
        unsigned mby = (unsigned)(((rb ? mw1 : mw0) >> kloc) & 0xFFull);
        union { bf16x8 v; unsigned u[4]; } ua;
#pragma unroll
        for (int p = 0; p < 4; ++p) {
          float s0 = f1v[rb] + f2e[2*p];
          float l0 = fmaxf(s0, 0.2f*s0);
          float v0 = (mby & (1u << (2*p))) ? l0 : Zv[rb];
          float p0 = fexp2(__builtin_fmaf(v0, L2E, Cv[rb]));
          float s1 = f1v[rb] + f2e[2*p+1];
          float l1 = fmaxf(s1, 0.2f*s1);
          float v1 = (mby & (2u << (2*p))) ? l1 : Zv[rb];
          float p1 = fexp2(__builtin_fmaf(v1, L2E, Cv[rb]));
          ua.u[p] = pack_bf16x2(p0, p1);
        }
        af[rb] = ua.v;
      }
      int gg = ks*4 + quad;
#pragma unroll
      for (int cb = 0; cb < 16; ++cb) {
        bf16x8 bf = *(const bf16x8*)(Bt + (gg*260 + cb*16 + me)*8);
        acc[0][cb] = __builtin_amdgcn_mfma_f32_16x16x32_bf16(af[0], bf, acc[0][cb], 0, 0, 0);
        acc[1][cb] = __builtin_amdgcn_mfma_f32_16x16x32_bf16(af[1], bf, acc[1][cb], 0, 0, 0);
      }
    }
  }
#pragma unroll
  for (int rb = 0; rb < 2; ++rb) {
    int io = i0w + rb*16 + quad*4;
#pragma unroll
    for (int cb = 0; cb < 16; ++cb) {
      int f = cb*16 + me;
      float* hp = H32 + (((size_t)b*1024 + io)*3 + kl)*256 + f;
#pragma unroll
      for (int r = 0; r < 4; ++r)
        atomicAdd(hp + (size_t)r*768, acc[rb][cb][r]);
    }
  }
}

// ---------------- layer attention: s = tanh(H@Ww+bw)@Wc (MFMA, R1) ----------------
// H32 [49152 rows][256] fp32 -> A-fragments converted in registers.
// Ww staged once per block into LDS in B-fragment layout: [kk 0..7][cb 0..6][lane][j 0..7]
// Epilogue: contrib = sum_cb tanh(acc+bw)*Wc, butterfly over 16 col-lanes.

__global__ __launch_bounds__(256) void k_score(
    const float* __restrict__ H32, const float* __restrict__ Ww,
    const float* __restrict__ bwv, const float* __restrict__ Wcv, float* __restrict__ svals)
{
  __shared__ unsigned short Bs[8*7*64*8];   // 57344 B
  __shared__ float bwL[128], WcL[128];
  const int tid = threadIdx.x, lane = tid & 63, wid = tid >> 6;
  const int me = lane & 15, quad = lane >> 4;
  // stage Ww -> LDS (B-fragment layout), bw/Wc
  for (int idx = tid; idx < 3584; idx += 256) {
    int kk = idx / 448, rem = idx % 448;
    int cb = rem >> 6, l = rem & 63;
    int n = cb*16 + (l & 15);
    int kbase = kk*32 + (l >> 4)*8;
    ushort4 lo, hi;
    if (n < 100) {
      const float* wp = Ww + (size_t)kbase*100 + n;
      lo.x = f2bf(wp[0]);   lo.y = f2bf(wp[100]); lo.z = f2bf(wp[200]); lo.w = f2bf(wp[300]);
      hi.x = f2bf(wp[400]); hi.y = f2bf(wp[500]); hi.z = f2bf(wp[600]); hi.w = f2bf(wp[700]);
    } else {
      lo.x=lo.y=lo.z=lo.w=0; hi.x=hi.y=hi.z=hi.w=0;
    }
    ushort4* dst = (ushort4*)(Bs + (size_t)idx*8);
    dst[0] = lo; dst[1] = hi;
  }
  if (tid < 128) {
    bwL[tid] = (tid < 100) ? bwv[tid] : 0.0f;
    WcL[tid] = (tid < 100) ? Wcv[tid] : 0.0f;
  }
  __syncthreads();

  const int row0 = blockIdx.x*64 + wid*16;         // this wave's 16 rows
  const float* Arow = H32 + (size_t)(row0 + me)*256;
  f32x4 acc[7] = {};
#pragma unroll
  for (int kk = 0; kk < 8; ++kk) {
    const float* ap = Arow + kk*32 + quad*8;
    float4 a0 = *(const float4*)(ap);
    float4 a1 = *(const float4*)(ap + 4);
    union { bf16x8 v; unsigned u[4]; } ua;
    ua.u[0] = pack_bf16x2(a0.x, a0.y);
    ua.u[1] = pack_bf16x2(a0.z, a0.w);
    ua.u[2] = pack_bf16x2(a1.x, a1.y);
    ua.u[3] = pack_bf16x2(a1.z, a1.w);
#pragma unroll
    for (int cb = 0; cb < 7; ++cb) {
      bf16x8 bf = *(const bf16x8*)(Bs + ((size_t)(kk*7 + cb)*64 + lane)*8);
      acc[cb] = __builtin_amdgcn_mfma_f32_16x16x32_bf16(ua.v, bf, acc[cb], 0, 0, 0);
    }
  }
  // epilogue: per output row r (quad*4+r), sum over 100 cols
#pragma unroll
  for (int r = 0; r < 4; ++r) {
    float contrib = 0.0f;
#pragma unroll
    for (int cb = 0; cb < 7; ++cb) {
      int col = cb*16 + me;
      contrib += tanh_fast(acc[cb][r] + bwL[col]) * WcL[col];
    }
    contrib += __shfl_xor(contrib, 1);
    contrib += __shfl_xor(contrib, 2);
    contrib += __shfl_xor(contrib, 4);
    contrib += __shfl_xor(contrib, 8);
    if (me == 0) svals[row0 + quad*4 + r] = contrib;
  }
}

__global__ void k_combine(const float* __restrict__ svals, const float* __restrict__ H32,
                          float* __restrict__ out)
{
  int tid = blockIdx.x*256 + threadIdx.x;
  int fq = tid & 63, bn = tid >> 6;
  float s0 = svals[bn*3], s1 = svals[bn*3+1], s2 = svals[bn*3+2];
  float mm = fmaxf(s0, fmaxf(s1, s2));
  float e0 = fexp2((s0-mm)*L2E), e1 = fexp2((s1-mm)*L2E), e2 = fexp2((s2-mm)*L2E);
  float inv = frcp(e0 + e1 + e2);
  const f32x4* h0 = (const f32x4*)(H32 + (size_t)bn*768) + fq;
  const f32x4* h1 = (const f32x4*)(H32 + (size_t)bn*768 + 256) + fq;
  const f32x4* h2 = (const f32x4*)(H32 + (size_t)bn*768 + 512) + fq;
  f32x4 r = (e0*(*h0) + e1*(*h1) + e2*(*h2))*inv;
  *((f32x4*)out + (size_t)bn*64 + fq) = r;
}

// ---------------- launcher ----------------

extern "C" void kernel_launch(void* const* d_in, const int* in_sizes, int n_in,
                              void* d_out, int out_size, void* d_ws, size_t ws_size,
                              hipStream_t stream) {
  const float* adj = (const float*)d_in[0];
  const float* X   = (const float*)d_in[1];
  const float* W   = (const float*)d_in[2];
  const float* a1  = (const float*)d_in[3];
  const float* a2  = (const float*)d_in[4];
  const float* Ww  = (const float*)d_in[5];
  const float* bw  = (const float*)d_in[6];
  const float* Wc  = (const float*)d_in[7];
  float* out = (float*)d_out;
  char* ws = (char*)d_ws;

  unsigned short* Xs  = (unsigned short*)(ws + 0);
  unsigned short* Wb  = (unsigned short*)(ws + 16777216);
  float* H32          = (float*)(ws + 0);                // reuses Xs/Wb region
  unsigned short* hsw = (unsigned short*)(ws + 50331648);
  u64* mbA            = (u64*)(ws + 125829120);
  u64* mbT            = (u64*)(ws + 138412032);
  float* fbuf         = (float*)(ws + 157286400);
  float* rowC         = (float*)(ws + 158466048);
  float* rowZ         = (float*)(ws + 159055872);
  float* svals        = (float*)(ws + 159645696);

  k_build_wb<<<608, 256, 0, stream>>>(W, a1, a2, Wb);
  k_xconv<<<4096, 256, 0, stream>>>(X, Xs);
  k_bitpack<<<196608, 256, 0, stream>>>(adj, mbA, mbT);
  k_boolmm<<<3072, 256, 0, stream>>>(mbA, mbA, mbA + 786432, mbT, 3);
  k_boolmm<<<3072, 256, 0, stream>>>(mbA + 786432, mbA, (u64*)nullptr, mbT, 6);
  k_gemm_h<<<2432, 256, 0, stream>>>(Xs, Wb, hsw, fbuf);
  hipMemsetAsync(H32, 0, 50331648, stream);
  k_rowstats<<<36864, 256, 0, stream>>>(mbT, fbuf, rowC, rowZ);
  k_attgemm<<<2304, 128, 0, stream>>>(hsw, fbuf, rowC, rowZ, mbT, H32);
  k_score<<<768, 256, 0, stream>>>(H32, Ww, bw, Wc, svals);
  k_combine<<<4096, 256, 0, stream>>>(svals, H32, out);
}

// Round 4
// 873.307 us; speedup vs baseline: 1.6352x; 1.0996x over previous
//
#include <hip/hip_runtime.h>

// MOGCN on MI355X. Pipeline:
//  k_build_wb : W[3,3,512,256] (+ W@a1, W@a2 cols) -> bf16, k-swizzled [64][2432][8]
//  k_xconv    : X fp32 -> bf16, k-swizzled [64][16384][8]
//  k_bitpack  : adj>0 -> bitset masks (level0), two layouts
//  k_boolmm   : boolean matrix power masks (adj^2>0, adj^3>0) via u64 OR-gather
//  k_gemm_h   : [16384,512]@[512,2432] bf16 MFMA -> h (swizzled) + f1/f2 (fp32)
//  k_rowstats : per-row softmax stats -> C=-m*log2e-log2(l), Z (empty-row handling)
//  k_attgemm  : t-fused (3 relation types accumulated in regs, no atomics/memset),
//               single-barrier-per-iter software pipeline, ks-parity LDS halves.
//               R3 fix: mask prefetch t-stride 262144 (u64), not 16384 (that's the
//               b-stride; mbT = s*262144 + b*16384 + w*1024 + i).
//  k_score    : s = tanh(H@Ww+bw)@Wc  (MFMA GEMM)
//  k_combine  : softmax over layers, weighted sum -> out
//
// Workspace map (bytes), total 159,842,304 (~152.4 MiB):
//  [0)            Xs bf16 16,777,216 | Wb bf16 @16,777,216 (2,490,368)  -- dead after k_gemm_h
//  [0)            H32 fp32 50,331,648 (reuses region above; fully written by k_attgemm)
//  [50,331,648)   hsw bf16 75,497,472   [9][16][128][256][8]
//  [125,829,120)  mbA u64 12,582,912    [2 lvl][48][1024][16]
//  [138,412,032)  mbT u64 18,874,368    [9][16][16w][1024i]
//  [157,286,400)  fbuf fp32 1,179,648   [2][9][16384]
//  [158,466,048)  rowC 589,824 | [159,055,872) rowZ 589,824 | [159,645,696) svals 196,608

typedef unsigned long long u64;
typedef __attribute__((ext_vector_type(4))) float f32x4;
typedef __attribute__((ext_vector_type(8))) short bf16x8;

#define NEGF (-9.0e15f)
#define L2E 1.44269504f

__device__ __forceinline__ float fexp2(float x){
#if __has_builtin(__builtin_amdgcn_exp2f)
  return __builtin_amdgcn_exp2f(x);
#else
  return exp2f(x);
#endif
}
__device__ __forceinline__ float flog2(float x){
#if __has_builtin(__builtin_amdgcn_logf)
  return __builtin_amdgcn_logf(x);
#else
  return log2f(x);
#endif
}
__device__ __forceinline__ float frcp(float x){
#if __has_builtin(__builtin_amdgcn_rcpf)
  return __builtin_amdgcn_rcpf(x);
#else
  return 1.0f/x;
#endif
}
__device__ __forceinline__ unsigned short f2bf(float x){   // RNE
  union { float f; unsigned u; } a; a.f = x;
  unsigned r = a.u + 0x7FFFu + ((a.u >> 16) & 1u);
  return (unsigned short)(r >> 16);
}
__device__ __forceinline__ float bf2f(unsigned short h){
  union { unsigned u; float f; } a; a.u = ((unsigned)h) << 16; return a.f;
}
__device__ __forceinline__ unsigned pack_bf16x2(float lo, float hi){ // fast round
  union { float f; unsigned u; } a, b; a.f = lo; b.f = hi;
  unsigned ul = a.u + 0x8000u, uh = b.u + 0x8000u;
#if __has_builtin(__builtin_amdgcn_perm)
  return __builtin_amdgcn_perm(uh, ul, 0x07060302u);
#else
  return (ul >> 16) | (uh & 0xFFFF0000u);
#endif
}
__device__ __forceinline__ float tanh_fast(float x){
  float e = fexp2(x * 2.885390082f);  // exp(2x)
  return 1.0f - 2.0f*frcp(e + 1.0f);
}
__device__ __forceinline__ void async_cp16(void* lds, const void* g){
  __builtin_amdgcn_global_load_lds(
      (const __attribute__((address_space(1))) unsigned int*)g,
      (__attribute__((address_space(3))) unsigned int*)lds, 16, 0, 0);
}

// ---------------- prep kernels ----------------

__global__ void k_build_wb(const float* __restrict__ W, const float* __restrict__ a1,
                           const float* __restrict__ a2, unsigned short* __restrict__ Wb)
{
  int idx = blockIdx.x*256 + threadIdx.x;           // g*2432 + c
  if (idx >= 64*2432) return;
  int c = idx % 2432, g = idx / 2432;
  unsigned short o[8];
  if (c < 2304) {
    int s = c >> 8, f = c & 255, t = s % 3, klq = s / 3;   // s = kl*3 + t
    const float* wp = W + ((size_t)(t*3 + klq)*512)*256 + f;
#pragma unroll
    for (int e = 0; e < 8; ++e) o[e] = f2bf(wp[(size_t)(g*8 + e)*256]);
  } else if (c < 2322) {
    int c2 = c - 2304, s = c2 >> 1, t = s % 3, klq = s / 3;
    const float* av = ((c2 & 1) ? a2 : a1) + (t*3 + klq)*256;
    const float* wp = W + ((size_t)(t*3 + klq)*512)*256;
#pragma unroll
    for (int e = 0; e < 8; ++e) {
      float acc = 0.0f;
      const float* wr = wp + (size_t)(g*8 + e)*256;
      for (int f = 0; f < 256; ++f) acc += wr[f]*av[f];
      o[e] = f2bf(acc);
    }
  } else {
#pragma unroll
    for (int e = 0; e < 8; ++e) o[e] = 0;
  }
  ushort4 lo, hi;
  lo.x=o[0]; lo.y=o[1]; lo.z=o[2]; lo.w=o[3];
  hi.x=o[4]; hi.y=o[5]; hi.z=o[6]; hi.w=o[7];
  ushort4* dst = (ushort4*)(Wb + (size_t)idx*8);
  dst[0] = lo; dst[1] = hi;
}

__global__ void k_xconv(const float* __restrict__ X, unsigned short* __restrict__ Xs)
{
  int idx = blockIdx.x*256 + threadIdx.x;           // g*16384 + bn
  int bn = idx & 16383, g = idx >> 14;
  const float* xp = X + (size_t)bn*512 + g*8;
  ushort4 lo, hi;
  lo.x=f2bf(xp[0]); lo.y=f2bf(xp[1]); lo.z=f2bf(xp[2]); lo.w=f2bf(xp[3]);
  hi.x=f2bf(xp[4]); hi.y=f2bf(xp[5]); hi.z=f2bf(xp[6]); hi.w=f2bf(xp[7]);
  ushort4* dst = (ushort4*)(Xs + (size_t)idx*8);
  dst[0] = lo; dst[1] = hi;
}

__global__ void k_bitpack(const float* __restrict__ adj, u64* __restrict__ mbA0,
                          u64* __restrict__ mbT)
{
  size_t tid = (size_t)blockIdx.x*256 + threadIdx.x;  // adj[b][t][i][j]
  float v = adj[tid];
  u64 msk = __ballot(v > 0.0f);
  if ((threadIdx.x & 63) == 0) {
    size_t word = tid >> 6;
    int w = (int)(word & 15), i = (int)((word >> 4) & 1023);
    int bt = (int)(word >> 14);     // b*3 + t
    int t = bt % 3, b = bt / 3;
    mbA0[((size_t)(t*16 + b)*1024 + i)*16 + w] = msk;
    mbT[(((size_t)t*16 + b)*16 + w)*1024 + i] = msk;   // s = t for level 0
  }
}

__global__ void k_boolmm(const u64* __restrict__ A, const u64* __restrict__ Bm,
                         u64* __restrict__ outA, u64* __restrict__ outT, int sbase)
{
  int tid = blockIdx.x*256 + threadIdx.x;   // 48*1024*16
  int w = tid & 15, i = (tid >> 4) & 1023, tb = tid >> 14;
  const u64* Ar = A + ((size_t)tb*1024 + i)*16;
  const u64* Bb = Bm + (size_t)tb*16384;
  u64 acc = 0;
  for (int ww = 0; ww < 16; ++ww) {
    u64 aw = Ar[ww];
    while (aw) {
      int kk = __builtin_ctzll(aw);
      aw &= aw - 1;
      acc |= Bb[((size_t)(ww*64 + kk))*16 + w];
    }
  }
  if (outA) outA[((size_t)tb*1024 + i)*16 + w] = acc;
  int t = tb >> 4, bq = tb & 15;
  outT[(((size_t)(sbase + t)*16 + bq)*16 + w)*1024 + i] = acc;
}

// ---------------- h = X@W GEMM (bf16 MFMA), fused f1/f2 ----------------

__global__ __launch_bounds__(256) void k_gemm_h(
    const unsigned short* __restrict__ Xs, const unsigned short* __restrict__ Wb,
    unsigned short* __restrict__ hsw, float* __restrict__ fbuf)
{
  __shared__ unsigned short Asl[8*132*8 + 8];
  __shared__ unsigned short Bsl[8*132*8 + 8];
  const int tid = threadIdx.x, lane = tid & 63, wid = tid >> 6;
  int vb = blockIdx.x;                       // XCD swizzle: same mt -> same XCD
  int xc = vb & 7, mrest = vb >> 3;
  int mt = xc + 8*(mrest/19), nt = mrest % 19;
  const int M0 = mt << 7, N0 = nt << 7;
  const int wr = (wid >> 1) << 6, wc = (wid & 1) << 6;
  const int me = lane & 15;
  f32x4 acc[4][4] = {};
  for (int ks64 = 0; ks64 < 8; ++ks64) {
    __syncthreads();
#pragma unroll
    for (int c = 0; c < 4; ++c) {
      int chunk = wid*4 + c, g = chunk >> 1, hh = chunk & 1;
      int ldsoff = (g*132 + hh*64)*8;
      const unsigned short* gpA = Xs + ((size_t)(ks64*8 + g)*16384 + (M0 + hh*64 + lane))*8;
      async_cp16(Asl + ldsoff, gpA);
      const unsigned short* gpB = Wb + ((size_t)(ks64*8 + g)*2432 + (N0 + hh*64 + lane))*8;
      async_cp16(Bsl + ldsoff, gpB);
    }
    __syncthreads();
#pragma unroll
    for (int ks32 = 0; ks32 < 2; ++ks32) {
      const int kg = ks32*4 + (lane >> 4);
      bf16x8 afr[4], bfr[4];
#pragma unroll
      for (int rb = 0; rb < 4; ++rb)
        afr[rb] = *(const bf16x8*)(Asl + (kg*132 + wr + rb*16 + me)*8);
#pragma unroll
      for (int cb = 0; cb < 4; ++cb)
        bfr[cb] = *(const bf16x8*)(Bsl + (kg*132 + wc + cb*16 + me)*8);
#pragma unroll
      for (int rb = 0; rb < 4; ++rb)
#pragma unroll
        for (int cb = 0; cb < 4; ++cb)
          acc[rb][cb] = __builtin_amdgcn_mfma_f32_16x16x32_bf16(afr[rb], bfr[cb], acc[rb][cb], 0, 0, 0);
    }
  }
  const int quad = lane >> 4;
#pragma unroll
  for (int rb = 0; rb < 4; ++rb) {
    int jbase = M0 + wr + rb*16 + quad*4;
    int bidx = jbase >> 10, jn = jbase & 1023;
#pragma unroll
    for (int cb = 0; cb < 4; ++cb) {
      int c = N0 + wc + cb*16 + me;
      f32x4 v = acc[rb][cb];
      if (c < 2304) {
        int s = c >> 8, f = c & 255;
        ushort4 pk;
        pk.x = f2bf(v[0]); pk.y = f2bf(v[1]); pk.z = f2bf(v[2]); pk.w = f2bf(v[3]);
        *(ushort4*)(hsw + (size_t)s*4194304 + (size_t)bidx*262144 + ((jn>>3)*256 + f)*8 + (jn&7)) = pk;
      } else if (c < 2322) {
        int c2 = c - 2304, s = c2 >> 1, wh = c2 & 1;
        *(f32x4*)(fbuf + (size_t)wh*147456 + s*16384 + jbase) = v;
      }
    }
  }
}

// ---------------- per-row softmax stats ----------------

__global__ __launch_bounds__(256) void k_rowstats(
    const u64* __restrict__ mbT, const float* __restrict__ fbuf,
    float* __restrict__ rowC, float* __restrict__ rowZ)
{
  int gw = blockIdx.x*4 + (threadIdx.x >> 6);   // row id: (s*16+b)*1024 + i
  int lane = threadIdx.x & 63;
  int i = gw & 1023, sb = gw >> 10;
  int b = sb & 15, s = sb >> 4;
  const u64* mrow = mbT + (size_t)sb*16384 + i;
  const float* f1g = fbuf + s*16384 + b*1024;
  const float* f2g = fbuf + 147456 + s*16384 + b*1024;
  float f1i = f1g[i];
  float vals[16];
  float mmax = NEGF;
#pragma unroll
  for (int w = 0; w < 16; ++w) {
    u64 word = mrow[(size_t)w*1024];
    float f2v = f2g[w*64 + lane];
    float sv = f1i + f2v;
    float lk = fmaxf(sv, 0.2f*sv);
    float val = ((word >> lane) & 1ull) ? lk : NEGF;
    vals[w] = val;
    mmax = fmaxf(mmax, val);
  }
#pragma unroll
  for (int off = 32; off; off >>= 1) mmax = fmaxf(mmax, __shfl_xor(mmax, off));
  float l = 0.0f;
#pragma unroll
  for (int w = 0; w < 16; ++w) l += fexp2((vals[w] - mmax)*L2E);
#pragma unroll
  for (int off = 32; off; off >>= 1) l += __shfl_xor(l, off);
  if (lane == 0) {
    bool empty = (mmax < -8.0e15f);
    rowC[gw] = (empty ? 0.0f : -mmax*L2E) - flog2(l);
    rowZ[gw] = empty ? 0.0f : NEGF;
  }
}

// ---------------- fused attention GEMM: H = sum_t softmax(mask_t(e_t)) @ h_t --------
// t-fused + software-pipelined. Grid: [mt 0..7][kl 0..2][b 0..15] -> 384 blocks,
// 256 threads (4 waves x 32 rows). 96 iterations over (t, st, ks-half); LDS holds two
// 16.3 KB half-buffers keyed by ks parity; exactly ONE barrier per iteration, staging
// for iter i+1 issued right after it so the vmcnt drain at the next barrier waits on
// loads that are a full compute phase old. Plain stores (no atomics, no memset).

__global__ __launch_bounds__(256, 2) void k_attgemm(
    const unsigned short* __restrict__ hsw, const float* __restrict__ fbuf,
    const float* __restrict__ rowC, const float* __restrict__ rowZ,
    const u64* __restrict__ mbT, float* __restrict__ H32)
{
  __shared__ unsigned short Bts[2*4*260*8];   // 2 half-buffers, 16640B each
  const int tid = threadIdx.x, lane = tid & 63, wid = tid >> 6;
  const int me = lane & 15, quad = lane >> 4;
  int vb = blockIdx.x;
  int mt = vb / 48, klb = vb % 48;
  int kl = klb >> 4, b = klb & 15;
  const int i0w = mt*128 + wid*32;
  const int ir0 = i0w + me, ir1 = i0w + 16 + me;
  const unsigned short* hbase = hsw + (size_t)(kl*3)*4194304 + (size_t)b*262144;
  const float* fb1 = fbuf + (kl*3)*16384 + b*1024;
  const float* fb2 = fbuf + 147456 + (kl*3)*16384 + b*1024;
  const float* Cb = rowC + ((kl*3)*16 + b)*1024;
  const float* Zb = rowZ + ((kl*3)*16 + b)*1024;
  const u64* mb = mbT + (size_t)((kl*3)*16 + b)*16384;   // = (kl*3)*262144 + b*16384

  float f1v[2], Cv[2], Zv[2];
  f32x4 acc[2][16] = {};

  // seed: stage iter 0 (t=0, st=0, ks=0) into buffer 0
  {
    const unsigned short* hstage = hbase + wid*2048;
    unsigned short* lb = Bts + wid*2080;
#pragma unroll
    for (int c = 0; c < 4; ++c)
      async_cp16(lb + c*512, hstage + c*512 + lane*8);
  }
  u64 mw0 = mb[ir0], mw1 = mb[ir1];
  u64 nm0 = 0, nm1 = 0;

  for (int it = 0; it < 96; ++it) {
    const int tt = it >> 5, kk = it & 1;
    const int st = (it >> 1) & 15;
    if ((it & 31) == 0) {                 // t boundary: per-row constants for this t
      f1v[0] = fb1[tt*16384 + ir0]; f1v[1] = fb1[tt*16384 + ir1];
      Cv[0]  = Cb[tt*16384 + ir0];  Cv[1]  = Cb[tt*16384 + ir1];
      Zv[0]  = Zb[tt*16384 + ir0];  Zv[1]  = Zb[tt*16384 + ir1];
    }
    if (!kk && it) { mw0 = nm0; mw1 = nm1; }     // adopt prefetched masks

    __syncthreads();   // drains vmcnt: current half's loads issued one compute ago

    if (it + 1 < 96) {                    // stage next half into other buffer
      int nx = it + 1;
      int nt2 = nx >> 5, ns = (nx >> 1) & 15, nk = nx & 1;
      const unsigned short* hstage = hbase + (size_t)nt2*4194304 + ns*16384 + (nk*4 + wid)*2048;
      unsigned short* lb = Bts + nk*8320 + wid*2080;
#pragma unroll
      for (int c = 0; c < 4; ++c)
        async_cp16(lb + c*512, hstage + c*512 + lane*8);
    }
    if (kk && it + 1 < 96) {              // prefetch masks for next (t,st)
      int gid = (it + 1) >> 1;
      int nt2 = gid >> 4, ns = gid & 15;
      const u64* mr = mb + (size_t)nt2*262144 + ns*1024;   // R3 fix: t-stride is 262144
      nm0 = mr[ir0]; nm1 = mr[ir1];
    }

    // f2 for this 32-k chunk (uniform-per-quad addresses -> L1 broadcast)
    const float* f2p = fb2 + tt*16384 + st*64 + kk*32 + quad*8;
    float4 fa = *(const float4*)(f2p);
    float4 fb4 = *(const float4*)(f2p + 4);
    float f2e[8] = {fa.x, fa.y, fa.z, fa.w, fb4.x, fb4.y, fb4.z, fb4.w};

    bf16x8 af[2];
    const int kloc = kk*32 + quad*8;
#pragma unroll
    for (int rb = 0; rb < 2; ++rb) {
      unsigned mby = (unsigned)(((rb ? mw1 : mw0) >> kloc) & 0xFFull);
      union { bf16x8 v; unsigned u[4]; } ua;
#pragma unroll
      for (int p = 0; p < 4; ++p) {
        float s0 = f1v[rb] + f2e[2*p];
        float l0 = fmaxf(s0, 0.2f*s0);
        float v0 = (mby & (1u << (2*p))) ? l0 : Zv[rb];
        float p0 = fexp2(__builtin_fmaf(v0, L2E, Cv[rb]));
        float s1 = f1v[rb] + f2e[2*p+1];
        float l1 = fmaxf(s1, 0.2f*s1);
        float v1 = (mby & (2u << (2*p))) ? l1 : Zv[rb];
        float p1 = fexp2(__builtin_fmaf(v1, L2E, Cv[rb]));
        ua.u[p] = pack_bf16x2(p0, p1);
      }
      af[rb] = ua.v;
    }
    const unsigned short* bbase = Bts + kk*8320 + quad*2080;
#pragma unroll
    for (int cb = 0; cb < 16; ++cb) {
      bf16x8 bf = *(const bf16x8*)(bbase + (cb*16 + me)*8);
      acc[0][cb] = __builtin_amdgcn_mfma_f32_16x16x32_bf16(af[0], bf, acc[0][cb], 0, 0, 0);
      acc[1][cb] = __builtin_amdgcn_mfma_f32_16x16x32_bf16(af[1], bf, acc[1][cb], 0, 0, 0);
    }
  }

  // epilogue: plain stores (each (kl,b,row,f) written exactly once)
#pragma unroll
  for (int rb = 0; rb < 2; ++rb) {
    int io = i0w + rb*16 + quad*4;
#pragma unroll
    for (int cb = 0; cb < 16; ++cb) {
      int f = cb*16 + me;
      float* hp = H32 + (((size_t)b*1024 + io)*3 + kl)*256 + f;
#pragma unroll
      for (int r = 0; r < 4; ++r)
        hp[(size_t)r*768] = acc[rb][cb][r];
    }
  }
}

// ---------------- layer attention: s = tanh(H@Ww+bw)@Wc (MFMA) ----------------

__global__ __launch_bounds__(256) void k_score(
    const float* __restrict__ H32, const float* __restrict__ Ww,
    const float* __restrict__ bwv, const float* __restrict__ Wcv, float* __restrict__ svals)
{
  __shared__ unsigned short Bs[8*7*64*8];   // 57344 B
  __shared__ float bwL[128], WcL[128];
  const int tid = threadIdx.x, lane = tid & 63, wid = tid >> 6;
  const int me = lane & 15, quad = lane >> 4;
  for (int idx = tid; idx < 3584; idx += 256) {
    int kk = idx / 448, rem = idx % 448;
    int cb = rem >> 6, l = rem & 63;
    int n = cb*16 + (l & 15);
    int kbase = kk*32 + (l >> 4)*8;
    ushort4 lo, hi;
    if (n < 100) {
      const float* wp = Ww + (size_t)kbase*100 + n;
      lo.x = f2bf(wp[0]);   lo.y = f2bf(wp[100]); lo.z = f2bf(wp[200]); lo.w = f2bf(wp[300]);
      hi.x = f2bf(wp[400]); hi.y = f2bf(wp[500]); hi.z = f2bf(wp[600]); hi.w = f2bf(wp[700]);
    } else {
      lo.x=lo.y=lo.z=lo.w=0; hi.x=hi.y=hi.z=hi.w=0;
    }
    ushort4* dst = (ushort4*)(Bs + (size_t)idx*8);
    dst[0] = lo; dst[1] = hi;
  }
  if (tid < 128) {
    bwL[tid] = (tid < 100) ? bwv[tid] : 0.0f;
    WcL[tid] = (tid < 100) ? Wcv[tid] : 0.0f;
  }
  __syncthreads();

  const int row0 = blockIdx.x*64 + wid*16;
  const float* Arow = H32 + (size_t)(row0 + me)*256;
  f32x4 acc[7] = {};
#pragma unroll
  for (int kk = 0; kk < 8; ++kk) {
    const float* ap = Arow + kk*32 + quad*8;
    float4 a0 = *(const float4*)(ap);
    float4 a1 = *(const float4*)(ap + 4);
    union { bf16x8 v; unsigned u[4]; } ua;
    ua.u[0] = pack_bf16x2(a0.x, a0.y);
    ua.u[1] = pack_bf16x2(a0.z, a0.w);
    ua.u[2] = pack_bf16x2(a1.x, a1.y);
    ua.u[3] = pack_bf16x2(a1.z, a1.w);
#pragma unroll
    for (int cb = 0; cb < 7; ++cb) {
      bf16x8 bf = *(const bf16x8*)(Bs + ((size_t)(kk*7 + cb)*64 + lane)*8);
      acc[cb] = __builtin_amdgcn_mfma_f32_16x16x32_bf16(ua.v, bf, acc[cb], 0, 0, 0);
    }
  }
#pragma unroll
  for (int r = 0; r < 4; ++r) {
    float contrib = 0.0f;
#pragma unroll
    for (int cb = 0; cb < 7; ++cb) {
      int col = cb*16 + me;
      contrib += tanh_fast(acc[cb][r] + bwL[col]) * WcL[col];
    }
    contrib += __shfl_xor(contrib, 1);
    contrib += __shfl_xor(contrib, 2);
    contrib += __shfl_xor(contrib, 4);
    contrib += __shfl_xor(contrib, 8);
    if (me == 0) svals[row0 + quad*4 + r] = contrib;
  }
}

__global__ void k_combine(const float* __restrict__ svals, const float* __restrict__ H32,
                          float* __restrict__ out)
{
  int tid = blockIdx.x*256 + threadIdx.x;
  int fq = tid & 63, bn = tid >> 6;
  float s0 = svals[bn*3], s1 = svals[bn*3+1], s2 = svals[bn*3+2];
  float mm = fmaxf(s0, fmaxf(s1, s2));
  float e0 = fexp2((s0-mm)*L2E), e1 = fexp2((s1-mm)*L2E), e2 = fexp2((s2-mm)*L2E);
  float inv = frcp(e0 + e1 + e2);
  const f32x4* h0 = (const f32x4*)(H32 + (size_t)bn*768) + fq;
  const f32x4* h1 = (const f32x4*)(H32 + (size_t)bn*768 + 256) + fq;
  const f32x4* h2 = (const f32x4*)(H32 + (size_t)bn*768 + 512) + fq;
  f32x4 r = (e0*(*h0) + e1*(*h1) + e2*(*h2))*inv;
  *((f32x4*)out + (size_t)bn*64 + fq) = r;
}

// ---------------- launcher ----------------

extern "C" void kernel_launch(void* const* d_in, const int* in_sizes, int n_in,
                              void* d_out, int out_size, void* d_ws, size_t ws_size,
                              hipStream_t stream) {
  const float* adj = (const float*)d_in[0];
  const float* X   = (const float*)d_in[1];
  const float* W   = (const float*)d_in[2];
  const float* a1  = (const float*)d_in[3];
  const float* a2  = (const float*)d_in[4];
  const float* Ww  = (const float*)d_in[5];
  const float* bw  = (const float*)d_in[6];
  const float* Wc  = (const float*)d_in[7];
  float* out = (float*)d_out;
  char* ws = (char*)d_ws;

  unsigned short* Xs  = (unsigned short*)(ws + 0);
  unsigned short* Wb  = (unsigned short*)(ws + 16777216);
  float* H32          = (float*)(ws + 0);                // reuses Xs/Wb region
  unsigned short* hsw = (unsigned short*)(ws + 50331648);
  u64* mbA            = (u64*)(ws + 125829120);
  u64* mbT            = (u64*)(ws + 138412032);
  float* fbuf         = (float*)(ws + 157286400);
  float* rowC         = (float*)(ws + 158466048);
  float* rowZ         = (float*)(ws + 159055872);
  float* svals        = (float*)(ws + 159645696);

  k_build_wb<<<608, 256, 0, stream>>>(W, a1, a2, Wb);
  k_xconv<<<4096, 256, 0, stream>>>(X, Xs);
  k_bitpack<<<196608, 256, 0, stream>>>(adj, mbA, mbT);
  k_boolmm<<<3072, 256, 0, stream>>>(mbA, mbA, mbA + 786432, mbT, 3);
  k_boolmm<<<3072, 256, 0, stream>>>(mbA + 786432, mbA, (u64*)nullptr, mbT, 6);
  k_gemm_h<<<2432, 256, 0, stream>>>(Xs, Wb, hsw, fbuf);
  k_rowstats<<<36864, 256, 0, stream>>>(mbT, fbuf, rowC, rowZ);
  k_attgemm<<<384, 256, 0, stream>>>(hsw, fbuf, rowC, rowZ, mbT, H32);
  k_score<<<768, 256, 0, stream>>>(H32, Ww, bw, Wc, svals);
  k_combine<<<4096, 256, 0, stream>>>(svals, H32, out);
}

// Round 5
// 857.219 us; speedup vs baseline: 1.6659x; 1.0188x over previous
//
#include <hip/hip_runtime.h>

// MOGCN on MI355X. Pipeline:
//  k_build_wb : W[3,3,512,256] (+ W@a1, W@a2 cols) -> bf16, k-swizzled [64][2432][8]
//  k_xconv    : X fp32 -> bf16, k-swizzled [64][16384][8]
//  k_bitpack  : adj>0 -> bitset masks (level0), two layouts
//  k_boolmm   : boolean matrix power masks (adj^2>0, adj^3>0) via u64 OR-gather
//  k_gemm_h   : [16384,512]@[512,2432] bf16 MFMA -> h (swizzled) + f1/f2 (fp32)
//  k_rowstats : per-row softmax stats -> C=-m*log2e-log2(l), Z (empty-row handling)
//  k_attgemm  : t-fused masked-softmax @ h, software-pipelined (1 barrier/iter).
//               R4: grid 384->768 (64-row tiles, acc[16]) -> exactly 3 blocks/CU,
//               3 waves/SIMD for latency hiding; was 1.5 blocks/CU imbalanced.
//  k_score    : s = tanh(H@Ww+bw)@Wc  (MFMA GEMM)
//  k_combine  : softmax over layers, weighted sum -> out
//
// Workspace map (bytes), total 159,842,304 (~152.4 MiB):
//  [0)            Xs bf16 16,777,216 | Wb bf16 @16,777,216 (2,490,368)  -- dead after k_gemm_h
//  [0)            H32 fp32 50,331,648 (reuses region above; fully written by k_attgemm)
//  [50,331,648)   hsw bf16 75,497,472   [9][16][128][256][8]
//  [125,829,120)  mbA u64 12,582,912    [2 lvl][48][1024][16]
//  [138,412,032)  mbT u64 18,874,368    [9][16][16w][1024i]
//  [157,286,400)  fbuf fp32 1,179,648   [2][9][16384]
//  [158,466,048)  rowC 589,824 | [159,055,872) rowZ 589,824 | [159,645,696) svals 196,608

typedef unsigned long long u64;
typedef __attribute__((ext_vector_type(4))) float f32x4;
typedef __attribute__((ext_vector_type(8))) short bf16x8;

#define NEGF (-9.0e15f)
#define L2E 1.44269504f

__device__ __forceinline__ float fexp2(float x){
#if __has_builtin(__builtin_amdgcn_exp2f)
  return __builtin_amdgcn_exp2f(x);
#else
  return exp2f(x);
#endif
}
__device__ __forceinline__ float flog2(float x){
#if __has_builtin(__builtin_amdgcn_logf)
  return __builtin_amdgcn_logf(x);
#else
  return log2f(x);
#endif
}
__device__ __forceinline__ float frcp(float x){
#if __has_builtin(__builtin_amdgcn_rcpf)
  return __builtin_amdgcn_rcpf(x);
#else
  return 1.0f/x;
#endif
}
__device__ __forceinline__ unsigned short f2bf(float x){   // RNE
  union { float f; unsigned u; } a; a.f = x;
  unsigned r = a.u + 0x7FFFu + ((a.u >> 16) & 1u);
  return (unsigned short)(r >> 16);
}
__device__ __forceinline__ float bf2f(unsigned short h){
  union { unsigned u; float f; } a; a.u = ((unsigned)h) << 16; return a.f;
}
__device__ __forceinline__ unsigned pack_bf16x2(float lo, float hi){ // fast round
  union { float f; unsigned u; } a, b; a.f = lo; b.f = hi;
  unsigned ul = a.u + 0x8000u, uh = b.u + 0x8000u;
#if __has_builtin(__builtin_amdgcn_perm)
  return __builtin_amdgcn_perm(uh, ul, 0x07060302u);
#else
  return (ul >> 16) | (uh & 0xFFFF0000u);
#endif
}
__device__ __forceinline__ float tanh_fast(float x){
  float e = fexp2(x * 2.885390082f);  // exp(2x)
  return 1.0f - 2.0f*frcp(e + 1.0f);
}
__device__ __forceinline__ void async_cp16(void* lds, const void* g){
  __builtin_amdgcn_global_load_lds(
      (const __attribute__((address_space(1))) unsigned int*)g,
      (__attribute__((address_space(3))) unsigned int*)lds, 16, 0, 0);
}

// ---------------- prep kernels ----------------

__global__ void k_build_wb(const float* __restrict__ W, const float* __restrict__ a1,
                           const float* __restrict__ a2, unsigned short* __restrict__ Wb)
{
  int idx = blockIdx.x*256 + threadIdx.x;           // g*2432 + c
  if (idx >= 64*2432) return;
  int c = idx % 2432, g = idx / 2432;
  unsigned short o[8];
  if (c < 2304) {
    int s = c >> 8, f = c & 255, t = s % 3, klq = s / 3;   // s = kl*3 + t
    const float* wp = W + ((size_t)(t*3 + klq)*512)*256 + f;
#pragma unroll
    for (int e = 0; e < 8; ++e) o[e] = f2bf(wp[(size_t)(g*8 + e)*256]);
  } else if (c < 2322) {
    int c2 = c - 2304, s = c2 >> 1, t = s % 3, klq = s / 3;
    const float* av = ((c2 & 1) ? a2 : a1) + (t*3 + klq)*256;
    const float* wp = W + ((size_t)(t*3 + klq)*512)*256;
#pragma unroll
    for (int e = 0; e < 8; ++e) {
      float acc = 0.0f;
      const float* wr = wp + (size_t)(g*8 + e)*256;
      for (int f = 0; f < 256; ++f) acc += wr[f]*av[f];
      o[e] = f2bf(acc);
    }
  } else {
#pragma unroll
    for (int e = 0; e < 8; ++e) o[e] = 0;
  }
  ushort4 lo, hi;
  lo.x=o[0]; lo.y=o[1]; lo.z=o[2]; lo.w=o[3];
  hi.x=o[4]; hi.y=o[5]; hi.z=o[6]; hi.w=o[7];
  ushort4* dst = (ushort4*)(Wb + (size_t)idx*8);
  dst[0] = lo; dst[1] = hi;
}

__global__ void k_xconv(const float* __restrict__ X, unsigned short* __restrict__ Xs)
{
  int idx = blockIdx.x*256 + threadIdx.x;           // g*16384 + bn
  int bn = idx & 16383, g = idx >> 14;
  const float* xp = X + (size_t)bn*512 + g*8;
  ushort4 lo, hi;
  lo.x=f2bf(xp[0]); lo.y=f2bf(xp[1]); lo.z=f2bf(xp[2]); lo.w=f2bf(xp[3]);
  hi.x=f2bf(xp[4]); hi.y=f2bf(xp[5]); hi.z=f2bf(xp[6]); hi.w=f2bf(xp[7]);
  ushort4* dst = (ushort4*)(Xs + (size_t)idx*8);
  dst[0] = lo; dst[1] = hi;
}

__global__ void k_bitpack(const float* __restrict__ adj, u64* __restrict__ mbA0,
                          u64* __restrict__ mbT)
{
  size_t tid = (size_t)blockIdx.x*256 + threadIdx.x;  // adj[b][t][i][j]
  float v = adj[tid];
  u64 msk = __ballot(v > 0.0f);
  if ((threadIdx.x & 63) == 0) {
    size_t word = tid >> 6;
    int w = (int)(word & 15), i = (int)((word >> 4) & 1023);
    int bt = (int)(word >> 14);     // b*3 + t
    int t = bt % 3, b = bt / 3;
    mbA0[((size_t)(t*16 + b)*1024 + i)*16 + w] = msk;
    mbT[(((size_t)t*16 + b)*16 + w)*1024 + i] = msk;   // s = t for level 0
  }
}

__global__ void k_boolmm(const u64* __restrict__ A, const u64* __restrict__ Bm,
                         u64* __restrict__ outA, u64* __restrict__ outT, int sbase)
{
  int tid = blockIdx.x*256 + threadIdx.x;   // 48*1024*16
  int w = tid & 15, i = (tid >> 4) & 1023, tb = tid >> 14;
  const u64* Ar = A + ((size_t)tb*1024 + i)*16;
  const u64* Bb = Bm + (size_t)tb*16384;
  u64 acc = 0;
  for (int ww = 0; ww < 16; ++ww) {
    u64 aw = Ar[ww];
    while (aw) {
      int kk = __builtin_ctzll(aw);
      aw &= aw - 1;
      acc |= Bb[((size_t)(ww*64 + kk))*16 + w];
    }
  }
  if (outA) outA[((size_t)tb*1024 + i)*16 + w] = acc;
  int t = tb >> 4, bq = tb & 15;
  outT[(((size_t)(sbase + t)*16 + bq)*16 + w)*1024 + i] = acc;
}

// ---------------- h = X@W GEMM (bf16 MFMA), fused f1/f2 ----------------

__global__ __launch_bounds__(256) void k_gemm_h(
    const unsigned short* __restrict__ Xs, const unsigned short* __restrict__ Wb,
    unsigned short* __restrict__ hsw, float* __restrict__ fbuf)
{
  __shared__ unsigned short Asl[8*132*8 + 8];
  __shared__ unsigned short Bsl[8*132*8 + 8];
  const int tid = threadIdx.x, lane = tid & 63, wid = tid >> 6;
  int vb = blockIdx.x;                       // XCD swizzle: same mt -> same XCD
  int xc = vb & 7, mrest = vb >> 3;
  int mt = xc + 8*(mrest/19), nt = mrest % 19;
  const int M0 = mt << 7, N0 = nt << 7;
  const int wr = (wid >> 1) << 6, wc = (wid & 1) << 6;
  const int me = lane & 15;
  f32x4 acc[4][4] = {};
  for (int ks64 = 0; ks64 < 8; ++ks64) {
    __syncthreads();
#pragma unroll
    for (int c = 0; c < 4; ++c) {
      int chunk = wid*4 + c, g = chunk >> 1, hh = chunk & 1;
      int ldsoff = (g*132 + hh*64)*8;
      const unsigned short* gpA = Xs + ((size_t)(ks64*8 + g)*16384 + (M0 + hh*64 + lane))*8;
      async_cp16(Asl + ldsoff, gpA);
      const unsigned short* gpB = Wb + ((size_t)(ks64*8 + g)*2432 + (N0 + hh*64 + lane))*8;
      async_cp16(Bsl + ldsoff, gpB);
    }
    __syncthreads();
#pragma unroll
    for (int ks32 = 0; ks32 < 2; ++ks32) {
      const int kg = ks32*4 + (lane >> 4);
      bf16x8 afr[4], bfr[4];
#pragma unroll
      for (int rb = 0; rb < 4; ++rb)
        afr[rb] = *(const bf16x8*)(Asl + (kg*132 + wr + rb*16 + me)*8);
#pragma unroll
      for (int cb = 0; cb < 4; ++cb)
        bfr[cb] = *(const bf16x8*)(Bsl + (kg*132 + wc + cb*16 + me)*8);
#pragma unroll
      for (int rb = 0; rb < 4; ++rb)
#pragma unroll
        for (int cb = 0; cb < 4; ++cb)
          acc[rb][cb] = __builtin_amdgcn_mfma_f32_16x16x32_bf16(afr[rb], bfr[cb], acc[rb][cb], 0, 0, 0);
    }
  }
  const int quad = lane >> 4;
#pragma unroll
  for (int rb = 0; rb < 4; ++rb) {
    int jbase = M0 + wr + rb*16 + quad*4;
    int bidx = jbase >> 10, jn = jbase & 1023;
#pragma unroll
    for (int cb = 0; cb < 4; ++cb) {
      int c = N0 + wc + cb*16 + me;
      f32x4 v = acc[rb][cb];
      if (c < 2304) {
        int s = c >> 8, f = c & 255;
        ushort4 pk;
        pk.x = f2bf(v[0]); pk.y = f2bf(v[1]); pk.z = f2bf(v[2]); pk.w = f2bf(v[3]);
        *(ushort4*)(hsw + (size_t)s*4194304 + (size_t)bidx*262144 + ((jn>>3)*256 + f)*8 + (jn&7)) = pk;
      } else if (c < 2322) {
        int c2 = c - 2304, s = c2 >> 1, wh = c2 & 1;
        *(f32x4*)(fbuf + (size_t)wh*147456 + s*16384 + jbase) = v;
      }
    }
  }
}

// ---------------- per-row softmax stats ----------------

__global__ __launch_bounds__(256) void k_rowstats(
    const u64* __restrict__ mbT, const float* __restrict__ fbuf,
    float* __restrict__ rowC, float* __restrict__ rowZ)
{
  int gw = blockIdx.x*4 + (threadIdx.x >> 6);   // row id: (s*16+b)*1024 + i
  int lane = threadIdx.x & 63;
  int i = gw & 1023, sb = gw >> 10;
  int b = sb & 15, s = sb >> 4;
  const u64* mrow = mbT + (size_t)sb*16384 + i;
  const float* f1g = fbuf + s*16384 + b*1024;
  const float* f2g = fbuf + 147456 + s*16384 + b*1024;
  float f1i = f1g[i];
  float vals[16];
  float mmax = NEGF;
#pragma unroll
  for (int w = 0; w < 16; ++w) {
    u64 word = mrow[(size_t)w*1024];
    float f2v = f2g[w*64 + lane];
    float sv = f1i + f2v;
    float lk = fmaxf(sv, 0.2f*sv);
    float val = ((word >> lane) & 1ull) ? lk : NEGF;
    vals[w] = val;
    mmax = fmaxf(mmax, val);
  }
#pragma unroll
  for (int off = 32; off; off >>= 1) mmax = fmaxf(mmax, __shfl_xor(mmax, off));
  float l = 0.0f;
#pragma unroll
  for (int w = 0; w < 16; ++w) l += fexp2((vals[w] - mmax)*L2E);
#pragma unroll
  for (int off = 32; off; off >>= 1) l += __shfl_xor(l, off);
  if (lane == 0) {
    bool empty = (mmax < -8.0e15f);
    rowC[gw] = (empty ? 0.0f : -mmax*L2E) - flog2(l);
    rowZ[gw] = empty ? 0.0f : NEGF;
  }
}

// ---------------- fused attention GEMM: H = sum_t softmax(mask_t(e_t)) @ h_t --------
// R4: grid [g=kl*16+b 0..47][mt 0..15] -> 768 blocks = exactly 3/CU, 256 threads
// (4 waves x 16 rows), acc[16] (64 VGPRs). 96 iterations over (t, st, ks-half);
// one barrier per iteration; staging for iter i+1 issued right after it.

__global__ __launch_bounds__(256, 3) void k_attgemm(
    const unsigned short* __restrict__ hsw, const float* __restrict__ fbuf,
    const float* __restrict__ rowC, const float* __restrict__ rowZ,
    const u64* __restrict__ mbT, float* __restrict__ H32)
{
  __shared__ unsigned short Bts[2*4*260*8];   // 2 half-buffers, 16640B each
  const int tid = threadIdx.x, lane = tid & 63, wid = tid >> 6;
  const int me = lane & 15, quad = lane >> 4;
  int vb = blockIdx.x;
  int mt = vb & 15, g = vb >> 4;              // g = kl*16 + b
  int kl = g >> 4, b = g & 15;
  const int i0w = mt*64 + wid*16;
  const int ir0 = i0w + me;
  const unsigned short* hbase = hsw + (size_t)(kl*3)*4194304 + (size_t)b*262144;
  const float* fb1 = fbuf + (kl*3)*16384 + b*1024;
  const float* fb2 = fbuf + 147456 + (kl*3)*16384 + b*1024;
  const float* Cb = rowC + ((kl*3)*16 + b)*1024;
  const float* Zb = rowZ + ((kl*3)*16 + b)*1024;
  const u64* mb = mbT + (size_t)((kl*3)*16 + b)*16384;   // t-stride 262144 u64

  float f1v, Cv, Zv;
  f32x4 acc[16] = {};

  // seed: stage iter 0 (t=0, st=0, ks=0) into buffer 0
  {
    const unsigned short* hstage = hbase + wid*2048;
    unsigned short* lb = Bts + wid*2080;
#pragma unroll
    for (int c = 0; c < 4; ++c)
      async_cp16(lb + c*512, hstage + c*512 + lane*8);
  }
  u64 mw = mb[ir0];
  u64 nm = 0;

  for (int it = 0; it < 96; ++it) {
    const int tt = it >> 5, kk = it & 1;
    const int st = (it >> 1) & 15;
    if ((it & 31) == 0) {                 // t boundary: per-row constants for this t
      f1v = fb1[tt*16384 + ir0];
      Cv  = Cb[tt*16384 + ir0];
      Zv  = Zb[tt*16384 + ir0];
    }
    if (!kk && it) mw = nm;               // adopt prefetched mask

    __syncthreads();   // drains vmcnt: current half's loads issued one compute ago

    if (it + 1 < 96) {                    // stage next half into other buffer
      int nx = it + 1;
      int nt2 = nx >> 5, ns = (nx >> 1) & 15, nk = nx & 1;
      const unsigned short* hstage = hbase + (size_t)nt2*4194304 + ns*16384 + (nk*4 + wid)*2048;
      unsigned short* lb = Bts + nk*8320 + wid*2080;
#pragma unroll
      for (int c = 0; c < 4; ++c)
        async_cp16(lb + c*512, hstage + c*512 + lane*8);
    }
    if (kk && it + 1 < 96) {              // prefetch mask for next (t,st)
      int gid = (it + 1) >> 1;
      int nt2 = gid >> 4, ns = gid & 15;
      nm = mb[(size_t)nt2*262144 + ns*1024 + ir0];
    }

    // f2 for this 32-k chunk (uniform-per-quad addresses -> L1 broadcast)
    const float* f2p = fb2 + tt*16384 + st*64 + kk*32 + quad*8;
    float4 fa = *(const float4*)(f2p);
    float4 fb4 = *(const float4*)(f2p + 4);
    float f2e[8] = {fa.x, fa.y, fa.z, fa.w, fb4.x, fb4.y, fb4.z, fb4.w};

    const int kloc = kk*32 + quad*8;
    unsigned mby = (unsigned)((mw >> kloc) & 0xFFull);
    union { bf16x8 v; unsigned u[4]; } ua;
#pragma unroll
    for (int p = 0; p < 4; ++p) {
      float s0 = f1v + f2e[2*p];
      float l0 = fmaxf(s0, 0.2f*s0);
      float v0 = (mby & (1u << (2*p))) ? l0 : Zv;
      float p0 = fexp2(__builtin_fmaf(v0, L2E, Cv));
      float s1 = f1v + f2e[2*p+1];
      float l1 = fmaxf(s1, 0.2f*s1);
      float v1 = (mby & (2u << (2*p))) ? l1 : Zv;
      float p1 = fexp2(__builtin_fmaf(v1, L2E, Cv));
      ua.u[p] = pack_bf16x2(p0, p1);
    }
    const unsigned short* bbase = Bts + kk*8320 + quad*2080;
#pragma unroll
    for (int cb = 0; cb < 16; ++cb) {
      bf16x8 bf = *(const bf16x8*)(bbase + (cb*16 + me)*8);
      acc[cb] = __builtin_amdgcn_mfma_f32_16x16x32_bf16(ua.v, bf, acc[cb], 0, 0, 0);
    }
  }

  // epilogue: plain stores (each (kl,b,row,f) written exactly once)
  {
    int io = i0w + quad*4;
#pragma unroll
    for (int cb = 0; cb < 16; ++cb) {
      int f = cb*16 + me;
      float* hp = H32 + (((size_t)b*1024 + io)*3 + kl)*256 + f;
#pragma unroll
      for (int r = 0; r < 4; ++r)
        hp[(size_t)r*768] = acc[cb][r];
    }
  }
}

// ---------------- layer attention: s = tanh(H@Ww+bw)@Wc (MFMA) ----------------

__global__ __launch_bounds__(256) void k_score(
    const float* __restrict__ H32, const float* __restrict__ Ww,
    const float* __restrict__ bwv, const float* __restrict__ Wcv, float* __restrict__ svals)
{
  __shared__ unsigned short Bs[8*7*64*8];   // 57344 B
  __shared__ float bwL[128], WcL[128];
  const int tid = threadIdx.x, lane = tid & 63, wid = tid >> 6;
  const int me = lane & 15, quad = lane >> 4;
  for (int idx = tid; idx < 3584; idx += 256) {
    int kk = idx / 448, rem = idx % 448;
    int cb = rem >> 6, l = rem & 63;
    int n = cb*16 + (l & 15);
    int kbase = kk*32 + (l >> 4)*8;
    ushort4 lo, hi;
    if (n < 100) {
      const float* wp = Ww + (size_t)kbase*100 + n;
      lo.x = f2bf(wp[0]);   lo.y = f2bf(wp[100]); lo.z = f2bf(wp[200]); lo.w = f2bf(wp[300]);
      hi.x = f2bf(wp[400]); hi.y = f2bf(wp[500]); hi.z = f2bf(wp[600]); hi.w = f2bf(wp[700]);
    } else {
      lo.x=lo.y=lo.z=lo.w=0; hi.x=hi.y=hi.z=hi.w=0;
    }
    ushort4* dst = (ushort4*)(Bs + (size_t)idx*8);
    dst[0] = lo; dst[1] = hi;
  }
  if (tid < 128) {
    bwL[tid] = (tid < 100) ? bwv[tid] : 0.0f;
    WcL[tid] = (tid < 100) ? Wcv[tid] : 0.0f;
  }
  __syncthreads();

  const int row0 = blockIdx.x*64 + wid*16;
  const float* Arow = H32 + (size_t)(row0 + me)*256;
  f32x4 acc[7] = {};
#pragma unroll
  for (int kk = 0; kk < 8; ++kk) {
    const float* ap = Arow + kk*32 + quad*8;
    float4 a0 = *(const float4*)(ap);
    float4 a1 = *(const float4*)(ap + 4);
    union { bf16x8 v; unsigned u[4]; } ua;
    ua.u[0] = pack_bf16x2(a0.x, a0.y);
    ua.u[1] = pack_bf16x2(a0.z, a0.w);
    ua.u[2] = pack_bf16x2(a1.x, a1.y);
    ua.u[3] = pack_bf16x2(a1.z, a1.w);
#pragma unroll
    for (int cb = 0; cb < 7; ++cb) {
      bf16x8 bf = *(const bf16x8*)(Bs + ((size_t)(kk*7 + cb)*64 + lane)*8);
      acc[cb] = __builtin_amdgcn_mfma_f32_16x16x32_bf16(ua.v, bf, acc[cb], 0, 0, 0);
    }
  }
#pragma unroll
  for (int r = 0; r < 4; ++r) {
    float contrib = 0.0f;
#pragma unroll
    for (int cb = 0; cb < 7; ++cb) {
      int col = cb*16 + me;
      contrib += tanh_fast(acc[cb][r] + bwL[col]) * WcL[col];
    }
    contrib += __shfl_xor(contrib, 1);
    contrib += __shfl_xor(contrib, 2);
    contrib += __shfl_xor(contrib, 4);
    contrib += __shfl_xor(contrib, 8);
    if (me == 0) svals[row0 + quad*4 + r] = contrib;
  }
}

__global__ void k_combine(const float* __restrict__ svals, const float* __restrict__ H32,
                          float* __restrict__ out)
{
  int tid = blockIdx.x*256 + threadIdx.x;
  int fq = tid & 63, bn = tid >> 6;
  float s0 = svals[bn*3], s1 = svals[bn*3+1], s2 = svals[bn*3+2];
  float mm = fmaxf(s0, fmaxf(s1, s2));
  float e0 = fexp2((s0-mm)*L2E), e1 = fexp2((s1-mm)*L2E), e2 = fexp2((s2-mm)*L2E);
  float inv = frcp(e0 + e1 + e2);
  const f32x4* h0 = (const f32x4*)(H32 + (size_t)bn*768) + fq;
  const f32x4* h1 = (const f32x4*)(H32 + (size_t)bn*768 + 256) + fq;
  const f32x4* h2 = (const f32x4*)(H32 + (size_t)bn*768 + 512) + fq;
  f32x4 r = (e0*(*h0) + e1*(*h1) + e2*(*h2))*inv;
  *((f32x4*)out + (size_t)bn*64 + fq) = r;
}

// ---------------- launcher ----------------

extern "C" void kernel_launch(void* const* d_in, const int* in_sizes, int n_in,
                              void* d_out, int out_size, void* d_ws, size_t ws_size,
                              hipStream_t stream) {
  const float* adj = (const float*)d_in[0];
  const float* X   = (const float*)d_in[1];
  const float* W   = (const float*)d_in[2];
  const float* a1  = (const float*)d_in[3];
  const float* a2  = (const float*)d_in[4];
  const float* Ww  = (const float*)d_in[5];
  const float* bw  = (const float*)d_in[6];
  const float* Wc  = (const float*)d_in[7];
  float* out = (float*)d_out;
  char* ws = (char*)d_ws;

  unsigned short* Xs  = (unsigned short*)(ws + 0);
  unsigned short* Wb  = (unsigned short*)(ws + 16777216);
  float* H32          = (float*)(ws + 0);                // reuses Xs/Wb region
  unsigned short* hsw = (unsigned short*)(ws + 50331648);
  u64* mbA            = (u64*)(ws + 125829120);
  u64* mbT            = (u64*)(ws + 138412032);
  float* fbuf         = (float*)(ws + 157286400);
  float* rowC         = (float*)(ws + 158466048);
  float* rowZ         = (float*)(ws + 159055872);
  float* svals        = (float*)(ws + 159645696);

  k_build_wb<<<608, 256, 0, stream>>>(W, a1, a2, Wb);
  k_xconv<<<4096, 256, 0, stream>>>(X, Xs);
  k_bitpack<<<196608, 256, 0, stream>>>(adj, mbA, mbT);
  k_boolmm<<<3072, 256, 0, stream>>>(mbA, mbA, mbA + 786432, mbT, 3);
  k_boolmm<<<3072, 256, 0, stream>>>(mbA + 786432, mbA, (u64*)nullptr, mbT, 6);
  k_gemm_h<<<2432, 256, 0, stream>>>(Xs, Wb, hsw, fbuf);
  k_rowstats<<<36864, 256, 0, stream>>>(mbT, fbuf, rowC, rowZ);
  k_attgemm<<<768, 256, 0, stream>>>(hsw, fbuf, rowC, rowZ, mbT, H32);
  k_score<<<768, 256, 0, stream>>>(H32, Ww, bw, Wc, svals);
  k_combine<<<4096, 256, 0, stream>>>(svals, H32, out);
}